// Round 1
// baseline (387.833 us; speedup 1.0000x reference)
//
#include <hip/hip_runtime.h>

// Self-attention forward. Inputs f32: x[4,2048,1024], Wqkv[1024,3072],
// bqkv[3072], Wout[1024,1024], bout[1024]; mask[4,2048,2048] int32.
// Output f32 [4,2048,1024].
//
// Round-7 change: all four GEMMs moved from the 128x128 2-barrier-per-K-step
// structure (576 TF, MfmaUtil 23%, 1.9e7 LDS bank conflicts) to a 256x256
// 8-wave ring-4 schedule with counted vmcnt (T3+T4), full XOR LDS swizzle
// (T2, via pre-swizzled global_load_lds source + swizzled ds_read offsets),
// and setprio around the MFMA cluster (T5).
//   - BM=BN=256, BK=32, 512 thr = 2x4 waves, wave tile 128x64, 16x16x32 bf16.
//   - LDS: 4 ring slots x 32 KB; slot row r (128 B) = A[r] k-chunks 0-3 and
//     B[r] k-chunks 4-7, chunk physically placed at (chunk ^ (r&7)).
//   - Per K-tile: stage tile t+3 (4x global_load_lds w16), vmcnt(12) [3 tiles
//     in flight, never 0], barrier, 12x ds_read_b128, 32 MFMA, barrier.
//   - Tail: clamped re-stage into the dead slot keeps vmcnt immediate uniform.

typedef __attribute__((ext_vector_type(8))) short short8;
typedef __attribute__((ext_vector_type(4))) float f32x4;
typedef unsigned short u16;

#define SEQ 2048
#define NB 4

static __device__ __forceinline__ u16 f2bf(float f) {
    unsigned int u = __builtin_bit_cast(unsigned int, f);
    u += 0x7fffu + ((u >> 16) & 1u);   // RNE
    return (u16)(u >> 16);
}
static __device__ __forceinline__ float bf2f(u16 h) {
    unsigned int u = ((unsigned int)h) << 16;
    return __builtin_bit_cast(float, u);
}

// async global->LDS, 16 bytes/lane. LDS dest = wave-uniform base + lane*16.
static __device__ __forceinline__ void gld16(u16* l, const u16* g) {
    __builtin_amdgcn_global_load_lds(
        (__attribute__((address_space(1))) void*)(g),
        (__attribute__((address_space(3))) void*)(l),
        16, 0, 0);
}

// f32 -> bf16, 8 elems/thread.
__global__ __launch_bounds__(256) void cvt_bf16(const float* __restrict__ s,
                                                u16* __restrict__ d, long n) {
    long i = ((long)blockIdx.x * 256 + threadIdx.x) * 8;
    if (i >= n) return;
    f32x4 a = *(const f32x4*)(s + i);
    f32x4 b = *(const f32x4*)(s + i + 4);
    short8 o;
    o[0] = (short)f2bf(a.x); o[1] = (short)f2bf(a.y);
    o[2] = (short)f2bf(a.z); o[3] = (short)f2bf(a.w);
    o[4] = (short)f2bf(b.x); o[5] = (short)f2bf(b.y);
    o[6] = (short)f2bf(b.z); o[7] = (short)f2bf(b.w);
    *(short8*)(d + i) = o;
}

// f32 [R][C] -> bf16 [C][R] (transpose + convert), 32x32 LDS tiles.
__global__ __launch_bounds__(256) void transpose_cvt(const float* __restrict__ in,
                                                     u16* __restrict__ out,
                                                     int R, int C) {
    __shared__ float t[32][33];
    const int c0 = blockIdx.x * 32;
    const int r0 = blockIdx.y * 32;
    const int x = threadIdx.x & 31;
    const int y = (threadIdx.x >> 5) * 4;
    #pragma unroll
    for (int i = 0; i < 4; i++)
        t[y + i][x] = in[(long)(r0 + y + i) * C + c0 + x];
    __syncthreads();
    #pragma unroll
    for (int i = 0; i < 4; i++)
        out[(long)(c0 + y + i) * R + r0 + x] = f2bf(t[x][y + i]);
}

// V slice of qkv (per batch [2048 s][1024 d], row stride 3072, col offset 2048)
// -> vt [b][1024 d][2048 s]. bf16 32x32 tile transpose.
__global__ __launch_bounds__(256) void transpose_v(const u16* __restrict__ qkv,
                                                   u16* __restrict__ vt) {
    __shared__ u16 t[32][33];
    const int b = blockIdx.z;
    const int s0 = blockIdx.y * 32;
    const int d0 = blockIdx.x * 32;
    const int x = threadIdx.x & 31;
    const int y = (threadIdx.x >> 5) * 4;
    const u16* src = qkv + (long)b * SEQ * 3072 + 2048;
    u16* dst = vt + (long)b * 1024 * SEQ;
    #pragma unroll
    for (int i = 0; i < 4; i++)
        t[y + i][x] = src[(long)(s0 + y + i) * 3072 + d0 + x];
    __syncthreads();
    #pragma unroll
    for (int i = 0; i < 4; i++)
        dst[(long)(d0 + y + i) * SEQ + s0 + x] = t[x][y + i];
}

// bf16 MFMA GEMM, 256x256 tile, ring-4 BK=32 pipeline (see header comment).
// C[m][n] = sum_k A[m][k] * Bt[n][k]   (Bt = B^T, [N][K] row-major).
// EPI 0: bf16 out + optional f32 bias.   EPI 1: bf16 out, *scale.
// EPI 2: f32 out + f32 bias.
// Requires: M,N multiples of 256; K multiple of 32 with K/32 >= 4.
template<int EPI>
__global__ __launch_bounds__(512, 2) void gemm256(
    const u16* __restrict__ Ap, long lda, long aBatch,
    const u16* __restrict__ Bp, long ldb, long bBatch,
    void* __restrict__ Cp, long ldc, long cBatch,
    const float* __restrict__ bias,
    float scale, int K)
{
    __shared__ __attribute__((aligned(16))) u16 lds[4][16384];  // 4 x 32 KB

    const int tid  = threadIdx.x;
    const int lane = tid & 63;
    const int wave = tid >> 6;          // 0..7
    const int wr   = wave >> 2;         // 0..1: wave row (128 M each)
    const int wc   = wave & 3;          // 0..3: wave col (64 N each)
    const int m16  = lane & 15;
    const int quad = lane >> 4;         // k-octet selector
    const int b    = blockIdx.z;
    const long m0  = (long)blockIdx.y * 256;
    const long n0  = (long)blockIdx.x * 256;

    const u16* A = Ap + (long)b * aBatch;
    const u16* B = Bp + (long)b * bBatch;

    // ---- staging lane constants (inverse-swizzled global source) ----
    // Physical LDS layout per slot: row r (0..255) x 8 chunks of 16 B.
    // Physical chunk p at row r holds logical chunk c = p ^ (r&7);
    // logical c in 0..3 = A[r] k-elems c*8..c*8+8, c in 4..7 = B[r] likewise.
    const int srow   = (lane >> 3) & 7;         // row within 8-row wave group
    const int lchunk = (lane & 7) ^ srow;       // logical chunk this lane loads
    const bool isA   = lchunk < 4;
    const int koff   = (lchunk & 3) * 8;        // u16 k offset within tile
    const long gld_  = isA ? lda : ldb;
    const u16* gsrc  = (isA ? A : B) + ((isA ? m0 : n0) + wave * 8 + srow) * gld_ + koff;
    const long gstep = gld_ * 64;               // 64 rows per 8 KB sweep

    // ---- fragment read constants (swizzled ds_read offsets) ----
    // A frag: row = wr*128 + mi*16 + m16, logical chunk = quad.
    // B frag: row = wc*64  + ni*16 + m16, logical chunk = 4 + quad.
    // row&7 == m16&7 for both, so the chunk offset is a lane constant.
    const int cswz = (quad ^ (m16 & 7)) * 8;    // u16 offset of A chunk

    f32x4 acc[8][4];
    #pragma unroll
    for (int mi = 0; mi < 8; mi++)
        #pragma unroll
        for (int ni = 0; ni < 4; ni++)
            acc[mi][ni] = (f32x4){0.f, 0.f, 0.f, 0.f};

    const int nt = K >> 5;

    // prologue: stage tiles 0..2 into slots 0..2 (12 loads in flight)
    for (int p = 0; p < 3; ++p) {
        const u16* g = gsrc + (long)p * 32;
        u16* l = (u16*)&lds[p][wave * 512];
        #pragma unroll
        for (int s = 0; s < 4; ++s) gld16(l + s * 4096, g + s * gstep);
    }

    for (int t = 0; t < nt; ++t) {
        // stage tile t+3 (clamped at the tail: re-reads last tile into the
        // dead slot (t-1)&3, keeping vmcnt accounting uniform)
        {
            const int kt = (t + 3 < nt) ? (t + 3) : (nt - 1);
            const u16* g = gsrc + (long)kt * 32;
            u16* l = (u16*)&lds[(t + 3) & 3][wave * 512];
            #pragma unroll
            for (int s = 0; s < 4; ++s) gld16(l + s * 4096, g + s * gstep);
        }
        // tile t's 4 loads are the oldest of 16 outstanding -> wait to 12.
        asm volatile("s_waitcnt vmcnt(12)" ::: "memory");
        __builtin_amdgcn_s_barrier();           // all waves: tile t in LDS
        asm volatile("" ::: "memory");

        const u16* sl = lds[t & 3];
        const u16* fa = sl + (wr * 128 + m16) * 64 + cswz;
        const u16* fb = sl + (wc * 64  + m16) * 64 + (cswz ^ 32);
        short8 af[8], bf[4];
        #pragma unroll
        for (int mi = 0; mi < 8; ++mi)
            af[mi] = *(const short8*)(fa + mi * 1024);
        #pragma unroll
        for (int ni = 0; ni < 4; ++ni)
            bf[ni] = *(const short8*)(fb + ni * 1024);

        __builtin_amdgcn_s_setprio(1);
        #pragma unroll
        for (int mi = 0; mi < 8; ++mi)
            #pragma unroll
            for (int ni = 0; ni < 4; ++ni)
                acc[mi][ni] = __builtin_amdgcn_mfma_f32_16x16x32_bf16(
                    af[mi], bf[ni], acc[mi][ni], 0, 0, 0);
        __builtin_amdgcn_s_setprio(0);
        asm volatile("" ::: "memory");
        __builtin_amdgcn_s_barrier();           // reads of slot t&3 retired;
                                                // safe to re-stage next iter
    }

    // D mapping per 16x16 frag: col = lane&15, row = quad*4 + r
    const long row0 = m0 + wr * 128 + quad * 4;
    if (EPI == 0) {
        u16* C = (u16*)Cp + (long)b * cBatch;
        #pragma unroll
        for (int ni = 0; ni < 4; ++ni) {
            const long col = n0 + wc * 64 + ni * 16 + m16;
            const float bv = bias ? bias[col] : 0.f;
            #pragma unroll
            for (int mi = 0; mi < 8; ++mi)
                #pragma unroll
                for (int r = 0; r < 4; ++r)
                    C[(row0 + mi * 16 + r) * ldc + col] = f2bf(acc[mi][ni][r] + bv);
        }
    } else if (EPI == 1) {
        u16* C = (u16*)Cp + (long)b * cBatch;
        #pragma unroll
        for (int ni = 0; ni < 4; ++ni) {
            const long col = n0 + wc * 64 + ni * 16 + m16;
            #pragma unroll
            for (int mi = 0; mi < 8; ++mi)
                #pragma unroll
                for (int r = 0; r < 4; ++r)
                    C[(row0 + mi * 16 + r) * ldc + col] = f2bf(acc[mi][ni][r] * scale);
        }
    } else {
        float* C = (float*)Cp + (long)b * cBatch;
        #pragma unroll
        for (int ni = 0; ni < 4; ++ni) {
            const long col = n0 + wc * 64 + ni * 16 + m16;
            const float bv = bias ? bias[col] : 0.f;
            #pragma unroll
            for (int mi = 0; mi < 8; ++mi)
                #pragma unroll
                for (int r = 0; r < 4; ++r)
                    C[(row0 + mi * 16 + r) * ldc + col] = acc[mi][ni][r] + bv;
        }
    }
}

// in-place masked row softmax over 2048 bf16 (f32 math). 1 block per row.
// mask==0 -> score := 1e-10 (applied here in f32; coalesced uint4 reads).
__global__ __launch_bounds__(256) void softmax2048(u16* __restrict__ S,
                                                   const int* __restrict__ mask) {
    const long row = blockIdx.x;
    u16* p = S + row * SEQ;
    const int* mrow = mask + row * SEQ;   // mask rows match sc rows (b*2048+q)
    const int tid = threadIdx.x;

    short8 v = *(const short8*)(p + tid * 8);
    uint4 mw0 = *(const uint4*)(mrow + tid * 8);
    uint4 mw1 = *(const uint4*)(mrow + tid * 8 + 4);
    const unsigned int* mwv = (const unsigned int*)&mw0;

    float f[8];
    #pragma unroll
    for (int j = 0; j < 8; j++) {
        const unsigned int mv = (j < 4) ? mwv[j] : ((const unsigned int*)&mw1)[j - 4];
        f[j] = (mv == 0u) ? 1e-10f : bf2f((u16)v[j]);
    }

    float m = f[0];
    #pragma unroll
    for (int j = 1; j < 8; j++) m = fmaxf(m, f[j]);
    #pragma unroll
    for (int i = 1; i < 64; i <<= 1) m = fmaxf(m, __shfl_xor(m, i));

    __shared__ float redm[4], reds[4];
    if ((tid & 63) == 0) redm[tid >> 6] = m;
    __syncthreads();
    m = fmaxf(fmaxf(redm[0], redm[1]), fmaxf(redm[2], redm[3]));

    float e[8], s = 0.f;
    #pragma unroll
    for (int j = 0; j < 8; j++) { e[j] = __expf(f[j] - m); s += e[j]; }
    #pragma unroll
    for (int i = 1; i < 64; i <<= 1) s += __shfl_xor(s, i);
    if ((tid & 63) == 0) reds[tid >> 6] = s;
    __syncthreads();
    s = reds[0] + reds[1] + reds[2] + reds[3];

    const float inv = 1.f / s;
    short8 o;
    #pragma unroll
    for (int j = 0; j < 8; j++) o[j] = (short)f2bf(e[j] * inv);
    *(short8*)(p + tid * 8) = o;
}

extern "C" void kernel_launch(void* const* d_in, const int* in_sizes, int n_in,
                              void* d_out, int out_size, void* d_ws, size_t ws_size,
                              hipStream_t stream) {
    const float* x    = (const float*)d_in[0];
    const int*   mask = (const int*)d_in[1];
    const float* Wqkv = (const float*)d_in[2];
    const float* bqkv = (const float*)d_in[3];
    const float* Wout = (const float*)d_in[4];
    const float* bout = (const float*)d_in[5];
    float* out = (float*)d_out;

    char* ws = (char*)d_ws;
    // ws layout, total 102,760,448 bytes:
    //   [0,        16777216) xh  bf16 [8192][1024]          (cvt -> K1)
    //   [16777216, 23068672) wqt bf16 [3072][1024]          (cvt -> K1)
    //   [0,        33554432) sc  bf16 [4][2048][2048]       (K2 -> K4; xh,wqt dead)
    //   [33554432, 35651584) wot bf16 [1024][1024]          (cvt -> K5)
    //   [35651584, 85983232) qkv bf16 [8192][3072]          (K1 -> K2)
    //   [35651584, 52428800) attn bf16 [8192][1024]         (K4 -> K5; qkv dead)
    //   [85983232,102760448) vt  bf16 [4][1024][2048]       (transpose_v -> K4)
    u16* xh   = (u16*)(ws + 0);
    u16* wqt  = (u16*)(ws + 16777216);
    u16* sc   = (u16*)(ws + 0);
    u16* wot  = (u16*)(ws + 33554432);
    u16* qkv  = (u16*)(ws + 35651584);
    u16* attn = (u16*)(ws + 35651584);
    u16* vt   = (u16*)(ws + 85983232);

    cvt_bf16<<<4096, 256, 0, stream>>>(x, xh, 8388608);
    transpose_cvt<<<dim3(96, 32), 256, 0, stream>>>(Wqkv, wqt, 1024, 3072);
    transpose_cvt<<<dim3(32, 32), 256, 0, stream>>>(Wout, wot, 1024, 1024);

    // K1: qkv = x @ Wqkv + bqkv   (M=8192, N=3072, K=1024), bf16 out
    gemm256<0><<<dim3(12, 32, 1), 512, 0, stream>>>(
        xh, 1024, 0, wqt, 1024, 0, qkv, 3072, 0, bqkv, 1.f, 1024);

    // V slice -> vt [b][d][s]
    transpose_v<<<dim3(32, 64, NB), 256, 0, stream>>>(qkv, vt);

    // K2: sc[b] = (Q[b] @ K[b]^T)/32   (M=N=2048, K=1024), bf16 out
    gemm256<1><<<dim3(8, 8, NB), 512, 0, stream>>>(
        qkv, 3072, (long)SEQ * 3072, qkv + 1024, 3072, (long)SEQ * 3072,
        sc, SEQ, (long)SEQ * SEQ, nullptr, 0.03125f, 1024);

    // K3: masked softmax rows (mask==0 -> 1e-10, f32 math, bf16 storage)
    softmax2048<<<dim3(NB * SEQ), 256, 0, stream>>>(sc, mask);

    // K4: attn[b] = P[b] @ V[b]   (M=2048, N=1024, K=2048), bf16 out
    gemm256<0><<<dim3(4, 8, NB), 512, 0, stream>>>(
        sc, SEQ, (long)SEQ * SEQ, vt, SEQ, (long)1024 * SEQ,
        attn, 1024, (long)SEQ * 1024, nullptr, 1.f, 2048);

    // K5: out = attn @ Wout + bout   (M=8192, N=1024, K=1024), f32 out
    gemm256<2><<<dim3(4, 32, 1), 512, 0, stream>>>(
        attn, 1024, 0, wot, 1024, 0, out, 1024, 0, bout, 1.f, 1024);
}

// Round 2
// 351.309 us; speedup vs baseline: 1.1040x; 1.1040x over previous
//
#include <hip/hip_runtime.h>

// Self-attention forward. Inputs f32: x[4,2048,1024], Wqkv[1024,3072],
// bqkv[3072], Wout[1024,1024], bout[1024]; mask[4,2048,2048] int32.
// Output f32 [4,2048,1024].
//
// Round-8: true 8-phase schedule (T3+T4) for all four GEMMs.
//   - BM=BN=256, 512 thr = 8 waves, 2 K-tiles (BK=64 each) per iteration.
//   - Each phase = one block-level 128x128 C-quadrant: all 8 waves cooperate
//     (wave sub-tile 32x64 -> 2mi x 4ni x 2ks = 16 MFMA). Quadrant order
//     (0,0),(1,0),(1,1),(0,1); A/B frags held in regs across phases so each
//     16 KB LDS stage unit dies one phase after its last LDS read.
//   - Per phase: {ds_read new frags; stage 1 half-tile (2x global_load_lds);
//     s_barrier; setprio(1); 16 MFMA; setprio(0); s_barrier}.
//   - Counted vmcnt(4) ONLY at phases 4 and 8 (2 half-tiles stay in flight,
//     never drained to 0). Stage->first-read distance >= 4 phases:
//       iter j stages: p1:buf1.A0(t2j+1) p2:buf1.B1(t2j+1) p3:buf0.B0(t2j+2)
//                      p4:buf0.A1 p5:buf0.A0 p6:buf0.B1 p7:buf1.B0(t2j+3)
//                      p8:buf1.A1(t2j+3)
//       p4-end vmcnt(4) covers p1,p2 (needed at p5,p7); p8-end vmcnt(4)
//       covers p3..p6 (needed at next p1..p3). Tail stages clamp kt.
//   - T2 XOR swizzle kept (phys chunk = logical ^ (row&7); inverse-swizzled
//     global source, swizzled ds_read offs — involution verified round 1).
//   - Raw s_barrier only (no __syncthreads: its vmcnt(0) drain is the
//     2-phase poison). Compiler-tracked ds_reads (fine lgkmcnt).

typedef __attribute__((ext_vector_type(8))) short short8;
typedef __attribute__((ext_vector_type(4))) float f32x4;
typedef unsigned short u16;

#define SEQ 2048
#define NB 4

static __device__ __forceinline__ u16 f2bf(float f) {
    unsigned int u = __builtin_bit_cast(unsigned int, f);
    u += 0x7fffu + ((u >> 16) & 1u);   // RNE
    return (u16)(u >> 16);
}
static __device__ __forceinline__ float bf2f(u16 h) {
    unsigned int u = ((unsigned int)h) << 16;
    return __builtin_bit_cast(float, u);
}

// async global->LDS, 16 bytes/lane. LDS dest = wave-uniform base + lane*16.
static __device__ __forceinline__ void gld16(u16* l, const u16* g) {
    __builtin_amdgcn_global_load_lds(
        (__attribute__((address_space(1))) void*)(g),
        (__attribute__((address_space(3))) void*)(l),
        16, 0, 0);
}

static __device__ __forceinline__ void bar() {
    asm volatile("" ::: "memory");
    __builtin_amdgcn_s_barrier();
    asm volatile("" ::: "memory");
}

// f32 -> bf16, 8 elems/thread.
__global__ __launch_bounds__(256) void cvt_bf16(const float* __restrict__ s,
                                                u16* __restrict__ d, long n) {
    long i = ((long)blockIdx.x * 256 + threadIdx.x) * 8;
    if (i >= n) return;
    f32x4 a = *(const f32x4*)(s + i);
    f32x4 b = *(const f32x4*)(s + i + 4);
    short8 o;
    o[0] = (short)f2bf(a.x); o[1] = (short)f2bf(a.y);
    o[2] = (short)f2bf(a.z); o[3] = (short)f2bf(a.w);
    o[4] = (short)f2bf(b.x); o[5] = (short)f2bf(b.y);
    o[6] = (short)f2bf(b.z); o[7] = (short)f2bf(b.w);
    *(short8*)(d + i) = o;
}

// f32 [R][C] -> bf16 [C][R] (transpose + convert), 32x32 LDS tiles.
__global__ __launch_bounds__(256) void transpose_cvt(const float* __restrict__ in,
                                                     u16* __restrict__ out,
                                                     int R, int C) {
    __shared__ float t[32][33];
    const int c0 = blockIdx.x * 32;
    const int r0 = blockIdx.y * 32;
    const int x = threadIdx.x & 31;
    const int y = (threadIdx.x >> 5) * 4;
    #pragma unroll
    for (int i = 0; i < 4; i++)
        t[y + i][x] = in[(long)(r0 + y + i) * C + c0 + x];
    __syncthreads();
    #pragma unroll
    for (int i = 0; i < 4; i++)
        out[(long)(c0 + y + i) * R + r0 + x] = f2bf(t[x][y + i]);
}

// V slice of qkv -> vt [b][1024 d][2048 s]. bf16 32x32 tile transpose.
__global__ __launch_bounds__(256) void transpose_v(const u16* __restrict__ qkv,
                                                   u16* __restrict__ vt) {
    __shared__ u16 t[32][33];
    const int b = blockIdx.z;
    const int s0 = blockIdx.y * 32;
    const int d0 = blockIdx.x * 32;
    const int x = threadIdx.x & 31;
    const int y = (threadIdx.x >> 5) * 4;
    const u16* src = qkv + (long)b * SEQ * 3072 + 2048;
    u16* dst = vt + (long)b * 1024 * SEQ;
    #pragma unroll
    for (int i = 0; i < 4; i++)
        t[y + i][x] = src[(long)(s0 + y + i) * 3072 + d0 + x];
    __syncthreads();
    #pragma unroll
    for (int i = 0; i < 4; i++)
        dst[(long)(d0 + y + i) * SEQ + s0 + x] = t[x][y + i];
}

// bf16 MFMA GEMM, 256x256 tile, 8-phase 2-buffer pipeline (header comment).
// C[m][n] = sum_k A[m][k] * Bt[n][k]   (Bt = B^T, [N][K] row-major).
// EPI 0: bf16 out + optional f32 bias.  EPI 1: bf16 out, *scale.
// EPI 2: f32 out + f32 bias.
// Requires: M,N multiples of 256; K multiple of 128.
template<int EPI>
__global__ __launch_bounds__(512, 2) void gemm256(
    const u16* __restrict__ Ap, long lda, long aBatch,
    const u16* __restrict__ Bp, long ldb, long bBatch,
    void* __restrict__ Cp, long ldc, long cBatch,
    const float* __restrict__ bias,
    float scale, int K)
{
    // 2 bufs x (A[256][64] + B[256][64]) bf16 = 2 x 64 KB = 128 KB.
    // u16 offsets: buf*32768; A unit h at h*8192; B unit h at 16384+h*8192.
    __shared__ __attribute__((aligned(16))) u16 lds[65536];

    const int tid  = threadIdx.x;
    const int lane = tid & 63;
    const int wave = tid >> 6;          // 0..7
    const int wrq  = wave >> 1;         // 0..3: 32-row band within quadrant
    const int wcq  = wave & 1;          // 0..1: 64-col band within quadrant
    const int m16  = lane & 15;
    const int quad = lane >> 4;
    const int b    = blockIdx.z;
    const long m0  = (long)blockIdx.y * 256;
    const long n0  = (long)blockIdx.x * 256;

    const u16* A = Ap + (long)b * aBatch;
    const u16* B = Bp + (long)b * bBatch;

    // staging lane constants (inverse-swizzled global source):
    // lane l writes phys chunk (l&7) of row (wave*8 + (l>>3)); that phys slot
    // holds logical chunk (l&7)^(row&7) = (l&7)^(l>>3).
    const int srow   = lane >> 3;
    const int schunk = (lane & 7) ^ srow;
    const u16* aSrc = A + (m0 + wave * 8 + srow) * lda + schunk * 8;
    const u16* bSrc = B + (n0 + wave * 8 + srow) * ldb + schunk * 8;

    // swizzled ds_read chunk offset (row&7 == m16&7 for all frag rows):
    const int cswz = (quad ^ (m16 & 7)) * 8;    // ks=1 -> cswz ^ 32
    const int arow = wrq * 32 + m16;            // + qr*8192/64 + mi*16
    const int brow = wcq * 64 + m16;

    short8 a0[2][2], a1[2][2], bq[2][4];        // [ks][mi] / [ks][ni]
    f32x4 acc[2][2][2][4];                      // [qr][qc][mi][ni]
    #pragma unroll
    for (int i = 0; i < 2; i++)
        #pragma unroll
        for (int j = 0; j < 2; j++)
            #pragma unroll
            for (int mi = 0; mi < 2; mi++)
                #pragma unroll
                for (int ni = 0; ni < 4; ni++)
                    acc[i][j][mi][ni] = (f32x4){0.f, 0.f, 0.f, 0.f};

    auto STAGE_A = [&](int buf, int h, int kt) {
        u16* l = (u16*)lds + buf * 32768 + h * 8192 + wave * 512;
        const u16* g = aSrc + (long)(h * 128) * lda + (long)kt * 64;
        gld16(l, g);
        gld16(l + 4096, g + (long)64 * lda);
    };
    auto STAGE_B = [&](int buf, int h, int kt) {
        u16* l = (u16*)lds + buf * 32768 + 16384 + h * 8192 + wave * 512;
        const u16* g = bSrc + (long)(h * 128) * ldb + (long)kt * 64;
        gld16(l, g);
        gld16(l + 4096, g + (long)64 * ldb);
    };
    auto RDA = [&](short8 (&d)[2][2], int buf, int qr) {
        const u16* p = (const u16*)lds + buf * 32768 + qr * 8192 + arow * 64;
        d[0][0] = *(const short8*)(p + cswz);
        d[0][1] = *(const short8*)(p + 1024 + cswz);
        d[1][0] = *(const short8*)(p + (cswz ^ 32));
        d[1][1] = *(const short8*)(p + 1024 + (cswz ^ 32));
    };
    auto RDB = [&](int buf, int qc) {
        const u16* p = (const u16*)lds + buf * 32768 + 16384 + qc * 8192 + brow * 64;
        #pragma unroll
        for (int ks = 0; ks < 2; ks++)
            #pragma unroll
            for (int ni = 0; ni < 4; ni++)
                bq[ks][ni] = *(const short8*)(p + ni * 1024 + (cswz ^ (ks * 32)));
    };
    auto MMA = [&](f32x4 (&c)[2][4], const short8 (&a)[2][2]) {
        __builtin_amdgcn_s_setprio(1);
        #pragma unroll
        for (int ks = 0; ks < 2; ks++)
            #pragma unroll
            for (int mi = 0; mi < 2; mi++)
                #pragma unroll
                for (int ni = 0; ni < 4; ni++)
                    c[mi][ni] = __builtin_amdgcn_mfma_f32_16x16x32_bf16(
                        a[ks][mi], bq[ks][ni], c[mi][ni], 0, 0, 0);
        __builtin_amdgcn_s_setprio(0);
    };

    const int nt = K >> 6;        // 64-wide K-tiles (nt >= 2, even)
    const int niter = nt >> 1;

    // prologue: tile 0 fully + tile 1's B0,A1; drain once; enter steady state.
    STAGE_B(0, 0, 0); STAGE_A(0, 1, 0); STAGE_A(0, 0, 0); STAGE_B(0, 1, 0);
    STAGE_B(1, 0, 1); STAGE_A(1, 1, 1);
    asm volatile("s_waitcnt vmcnt(0)" ::: "memory");
    __builtin_amdgcn_s_barrier();
    asm volatile("" ::: "memory");

    #pragma unroll 1
    for (int j = 0; j < niter; ++j) {
        const int t1 = 2 * j + 1;
        int t2 = 2 * j + 2; if (t2 > nt - 1) t2 = nt - 1;
        int t3 = 2 * j + 3; if (t3 > nt - 1) t3 = nt - 1;

        // ---- p1: T0.q(0,0) ----
        RDA(a0, 0, 0); RDB(0, 0);
        STAGE_A(1, 0, t1);
        bar();
        MMA(acc[0][0], a0);
        bar();
        // ---- p2: T0.q(1,0) ----
        RDA(a1, 0, 1);
        STAGE_B(1, 1, t1);
        bar();
        MMA(acc[1][0], a1);
        bar();
        // ---- p3: T0.q(1,1) ----
        RDB(0, 1);
        STAGE_B(0, 0, t2);
        bar();
        MMA(acc[1][1], a1);
        bar();
        // ---- p4: T0.q(0,1)  (a0, bq held in regs) ----
        STAGE_A(0, 1, t2);
        bar();
        MMA(acc[0][1], a0);
        asm volatile("s_waitcnt vmcnt(4)" ::: "memory");
        bar();
        // ---- p5: T1.q(0,0) ----
        RDA(a0, 1, 0); RDB(1, 0);
        STAGE_A(0, 0, t2);
        bar();
        MMA(acc[0][0], a0);
        bar();
        // ---- p6: T1.q(1,0) ----
        RDA(a1, 1, 1);
        STAGE_B(0, 1, t2);
        bar();
        MMA(acc[1][0], a1);
        bar();
        // ---- p7: T1.q(1,1) ----
        RDB(1, 1);
        STAGE_B(1, 0, t3);
        bar();
        MMA(acc[1][1], a1);
        bar();
        // ---- p8: T1.q(0,1) ----
        STAGE_A(1, 1, t3);
        bar();
        MMA(acc[0][1], a0);
        asm volatile("s_waitcnt vmcnt(4)" ::: "memory");
        bar();
    }

    // D mapping per 16x16 frag: col = lane&15, row = quad*4 + r.
    #pragma unroll
    for (int qr = 0; qr < 2; qr++) {
        const long row0 = m0 + qr * 128 + wrq * 32 + quad * 4;
        #pragma unroll
        for (int qc = 0; qc < 2; qc++) {
            #pragma unroll
            for (int ni = 0; ni < 4; ni++) {
                const long col = n0 + qc * 128 + wcq * 64 + ni * 16 + m16;
                if (EPI == 0) {
                    u16* C = (u16*)Cp + (long)b * cBatch;
                    const float bv = bias ? bias[col] : 0.f;
                    #pragma unroll
                    for (int mi = 0; mi < 2; mi++)
                        #pragma unroll
                        for (int r = 0; r < 4; r++)
                            C[(row0 + mi * 16 + r) * ldc + col] =
                                f2bf(acc[qr][qc][mi][ni][r] + bv);
                } else if (EPI == 1) {
                    u16* C = (u16*)Cp + (long)b * cBatch;
                    #pragma unroll
                    for (int mi = 0; mi < 2; mi++)
                        #pragma unroll
                        for (int r = 0; r < 4; r++)
                            C[(row0 + mi * 16 + r) * ldc + col] =
                                f2bf(acc[qr][qc][mi][ni][r] * scale);
                } else {
                    float* C = (float*)Cp + (long)b * cBatch;
                    const float bv = bias ? bias[col] : 0.f;
                    #pragma unroll
                    for (int mi = 0; mi < 2; mi++)
                        #pragma unroll
                        for (int r = 0; r < 4; r++)
                            C[(row0 + mi * 16 + r) * ldc + col] =
                                acc[qr][qc][mi][ni][r] + bv;
                }
            }
        }
    }
}

// in-place masked row softmax over 2048 bf16 (f32 math). 1 block per row.
__global__ __launch_bounds__(256) void softmax2048(u16* __restrict__ S,
                                                   const int* __restrict__ mask) {
    const long row = blockIdx.x;
    u16* p = S + row * SEQ;
    const int* mrow = mask + row * SEQ;
    const int tid = threadIdx.x;

    short8 v = *(const short8*)(p + tid * 8);
    uint4 mw0 = *(const uint4*)(mrow + tid * 8);
    uint4 mw1 = *(const uint4*)(mrow + tid * 8 + 4);
    const unsigned int* mwv = (const unsigned int*)&mw0;

    float f[8];
    #pragma unroll
    for (int j = 0; j < 8; j++) {
        const unsigned int mv = (j < 4) ? mwv[j] : ((const unsigned int*)&mw1)[j - 4];
        f[j] = (mv == 0u) ? 1e-10f : bf2f((u16)v[j]);
    }

    float m = f[0];
    #pragma unroll
    for (int j = 1; j < 8; j++) m = fmaxf(m, f[j]);
    #pragma unroll
    for (int i = 1; i < 64; i <<= 1) m = fmaxf(m, __shfl_xor(m, i));

    __shared__ float redm[4], reds[4];
    if ((tid & 63) == 0) redm[tid >> 6] = m;
    __syncthreads();
    m = fmaxf(fmaxf(redm[0], redm[1]), fmaxf(redm[2], redm[3]));

    float e[8], s = 0.f;
    #pragma unroll
    for (int j = 0; j < 8; j++) { e[j] = __expf(f[j] - m); s += e[j]; }
    #pragma unroll
    for (int i = 1; i < 64; i <<= 1) s += __shfl_xor(s, i);
    if ((tid & 63) == 0) reds[tid >> 6] = s;
    __syncthreads();
    s = reds[0] + reds[1] + reds[2] + reds[3];

    const float inv = 1.f / s;
    short8 o;
    #pragma unroll
    for (int j = 0; j < 8; j++) o[j] = (short)f2bf(e[j] * inv);
    *(short8*)(p + tid * 8) = o;
}

extern "C" void kernel_launch(void* const* d_in, const int* in_sizes, int n_in,
                              void* d_out, int out_size, void* d_ws, size_t ws_size,
                              hipStream_t stream) {
    const float* x    = (const float*)d_in[0];
    const int*   mask = (const int*)d_in[1];
    const float* Wqkv = (const float*)d_in[2];
    const float* bqkv = (const float*)d_in[3];
    const float* Wout = (const float*)d_in[4];
    const float* bout = (const float*)d_in[5];
    float* out = (float*)d_out;

    char* ws = (char*)d_ws;
    // ws layout, total 102,760,448 bytes:
    //   [0,        16777216) xh  bf16 [8192][1024]          (cvt -> K1)
    //   [16777216, 23068672) wqt bf16 [3072][1024]          (cvt -> K1)
    //   [0,        33554432) sc  bf16 [4][2048][2048]       (K2 -> K4; xh,wqt dead)
    //   [33554432, 35651584) wot bf16 [1024][1024]          (cvt -> K5)
    //   [35651584, 85983232) qkv bf16 [8192][3072]          (K1 -> K2)
    //   [35651584, 52428800) attn bf16 [8192][1024]         (K4 -> K5; qkv dead)
    //   [85983232,102760448) vt  bf16 [4][1024][2048]       (transpose_v -> K4)
    u16* xh   = (u16*)(ws + 0);
    u16* wqt  = (u16*)(ws + 16777216);
    u16* sc   = (u16*)(ws + 0);
    u16* wot  = (u16*)(ws + 33554432);
    u16* qkv  = (u16*)(ws + 35651584);
    u16* attn = (u16*)(ws + 35651584);
    u16* vt   = (u16*)(ws + 85983232);

    cvt_bf16<<<4096, 256, 0, stream>>>(x, xh, 8388608);
    transpose_cvt<<<dim3(96, 32), 256, 0, stream>>>(Wqkv, wqt, 1024, 3072);
    transpose_cvt<<<dim3(32, 32), 256, 0, stream>>>(Wout, wot, 1024, 1024);

    // K1: qkv = x @ Wqkv + bqkv   (M=8192, N=3072, K=1024), bf16 out
    gemm256<0><<<dim3(12, 32, 1), 512, 0, stream>>>(
        xh, 1024, 0, wqt, 1024, 0, qkv, 3072, 0, bqkv, 1.f, 1024);

    // V slice -> vt [b][d][s]
    transpose_v<<<dim3(32, 64, NB), 256, 0, stream>>>(qkv, vt);

    // K2: sc[b] = (Q[b] @ K[b]^T)/32   (M=N=2048, K=1024), bf16 out
    gemm256<1><<<dim3(8, 8, NB), 512, 0, stream>>>(
        qkv, 3072, (long)SEQ * 3072, qkv + 1024, 3072, (long)SEQ * 3072,
        sc, SEQ, (long)SEQ * SEQ, nullptr, 0.03125f, 1024);

    // K3: masked softmax rows (mask==0 -> 1e-10, f32 math, bf16 storage)
    softmax2048<<<dim3(NB * SEQ), 256, 0, stream>>>(sc, mask);

    // K4: attn[b] = P[b] @ V[b]   (M=2048, N=1024, K=2048), bf16 out
    gemm256<0><<<dim3(4, 8, NB), 512, 0, stream>>>(
        sc, SEQ, (long)SEQ * SEQ, vt, SEQ, (long)1024 * SEQ,
        attn, 1024, (long)SEQ * 1024, nullptr, 1.f, 2048);

    // K5: out = attn @ Wout + bout   (M=8192, N=1024, K=1024), f32 out
    gemm256<2><<<dim3(4, 32, 1), 512, 0, stream>>>(
        attn, 1024, 0, wot, 1024, 0, out, 1024, 0, bout, 1.f, 1024);
}

// Round 3
// 348.672 us; speedup vs baseline: 1.1123x; 1.0076x over previous
//
#include <hip/hip_runtime.h>

// Self-attention forward. Inputs f32: x[4,2048,1024], Wqkv[1024,3072],
// bqkv[3072], Wout[1024,1024], bout[1024]; mask[4,2048,2048] int32.
// Output f32 [4,2048,1024].
//
// Round-9: same 8-phase/256x256/2-buf geometry as round 8, but with the
// m201 template's exact fence discipline:
//   - bare __builtin_amdgcn_s_barrier() (NO asm memory-clobber wrappers:
//     round-8 wrapped all 16 barriers/iter in clobbers, which forces the
//     waitcnt inserter to drain pending loads per phase -> 500cy phases)
//   - bare asm s_waitcnt vmcnt(4) + sched_barrier(0) at phases 4/8 only
//   - s_waitcnt lgkmcnt(8) hint before barrier on 12-read phases
//   - clamp-free main loop + peeled final iteration (dead restages at
//     constant offsets keep vmcnt accounting uniform); running stage
//     pointers (+128/iter) make all phase address math loop-invariant.
// Stage->use and overwrite-safety distances unchanged from round 8.

typedef __attribute__((ext_vector_type(8))) short short8;
typedef __attribute__((ext_vector_type(4))) float f32x4;
typedef unsigned short u16;

#define SEQ 2048
#define NB 4

static __device__ __forceinline__ u16 f2bf(float f) {
    unsigned int u = __builtin_bit_cast(unsigned int, f);
    u += 0x7fffu + ((u >> 16) & 1u);   // RNE
    return (u16)(u >> 16);
}
static __device__ __forceinline__ float bf2f(u16 h) {
    unsigned int u = ((unsigned int)h) << 16;
    return __builtin_bit_cast(float, u);
}

// async global->LDS, 16 bytes/lane. LDS dest = wave-uniform base + lane*16.
static __device__ __forceinline__ void gld16(u16* l, const u16* g) {
    __builtin_amdgcn_global_load_lds(
        (__attribute__((address_space(1))) void*)(g),
        (__attribute__((address_space(3))) void*)(l),
        16, 0, 0);
}

// f32 -> bf16, 8 elems/thread.
__global__ __launch_bounds__(256) void cvt_bf16(const float* __restrict__ s,
                                                u16* __restrict__ d, long n) {
    long i = ((long)blockIdx.x * 256 + threadIdx.x) * 8;
    if (i >= n) return;
    f32x4 a = *(const f32x4*)(s + i);
    f32x4 b = *(const f32x4*)(s + i + 4);
    short8 o;
    o[0] = (short)f2bf(a.x); o[1] = (short)f2bf(a.y);
    o[2] = (short)f2bf(a.z); o[3] = (short)f2bf(a.w);
    o[4] = (short)f2bf(b.x); o[5] = (short)f2bf(b.y);
    o[6] = (short)f2bf(b.z); o[7] = (short)f2bf(b.w);
    *(short8*)(d + i) = o;
}

// f32 [R][C] -> bf16 [C][R] (transpose + convert), 32x32 LDS tiles.
__global__ __launch_bounds__(256) void transpose_cvt(const float* __restrict__ in,
                                                     u16* __restrict__ out,
                                                     int R, int C) {
    __shared__ float t[32][33];
    const int c0 = blockIdx.x * 32;
    const int r0 = blockIdx.y * 32;
    const int x = threadIdx.x & 31;
    const int y = (threadIdx.x >> 5) * 4;
    #pragma unroll
    for (int i = 0; i < 4; i++)
        t[y + i][x] = in[(long)(r0 + y + i) * C + c0 + x];
    __syncthreads();
    #pragma unroll
    for (int i = 0; i < 4; i++)
        out[(long)(c0 + y + i) * R + r0 + x] = f2bf(t[x][y + i]);
}

// V slice of qkv -> vt [b][1024 d][2048 s]. bf16 32x32 tile transpose.
__global__ __launch_bounds__(256) void transpose_v(const u16* __restrict__ qkv,
                                                   u16* __restrict__ vt) {
    __shared__ u16 t[32][33];
    const int b = blockIdx.z;
    const int s0 = blockIdx.y * 32;
    const int d0 = blockIdx.x * 32;
    const int x = threadIdx.x & 31;
    const int y = (threadIdx.x >> 5) * 4;
    const u16* src = qkv + (long)b * SEQ * 3072 + 2048;
    u16* dst = vt + (long)b * 1024 * SEQ;
    #pragma unroll
    for (int i = 0; i < 4; i++)
        t[y + i][x] = src[(long)(s0 + y + i) * 3072 + d0 + x];
    __syncthreads();
    #pragma unroll
    for (int i = 0; i < 4; i++)
        dst[(long)(d0 + y + i) * SEQ + s0 + x] = t[x][y + i];
}

// bf16 MFMA GEMM, 256x256 tile, 8-phase 2-buffer pipeline (header comment).
// C[m][n] = sum_k A[m][k] * Bt[n][k]   (Bt = B^T, [N][K] row-major).
// EPI 0: bf16 out + optional f32 bias.  EPI 1: bf16 out, *scale.
// EPI 2: f32 out + f32 bias.
// Requires: M,N multiples of 256; K multiple of 128.
template<int EPI>
__global__ __launch_bounds__(512, 2) void gemm256(
    const u16* __restrict__ Ap, long lda, long aBatch,
    const u16* __restrict__ Bp, long ldb, long bBatch,
    void* __restrict__ Cp, long ldc, long cBatch,
    const float* __restrict__ bias,
    float scale, int K)
{
    // 2 bufs x (A[256][64] + B[256][64]) bf16 = 2 x 64 KB = 128 KB.
    // u16 offsets: buf*32768; A unit h at h*8192; B unit h at 16384+h*8192.
    __shared__ __attribute__((aligned(16))) u16 lds[65536];

    const int tid  = threadIdx.x;
    const int lane = tid & 63;
    const int wave = tid >> 6;          // 0..7
    const int wrq  = wave >> 1;         // 0..3: 32-row band within quadrant
    const int wcq  = wave & 1;          // 0..1: 64-col band within quadrant
    const int m16  = lane & 15;
    const int quad = lane >> 4;
    const int b    = blockIdx.z;
    const long m0  = (long)blockIdx.y * 256;
    const long n0  = (long)blockIdx.x * 256;

    const u16* A = Ap + (long)b * aBatch;
    const u16* B = Bp + (long)b * bBatch;

    // staging lane constants (inverse-swizzled global source):
    // lane l writes phys chunk (l&7) of row (wave*8 + (l>>3)); that phys slot
    // holds logical chunk (l&7)^(row&7) = (l&7)^(l>>3).
    const int srow   = lane >> 3;
    const int schunk = (lane & 7) ^ srow;
    // running stage pointers: point at the K-tile pair base (tile 2j); all
    // per-phase offsets are then loop-invariant constants.
    const u16* aP = A + (m0 + wave * 8 + srow) * lda + schunk * 8;
    const u16* bP = B + (n0 + wave * 8 + srow) * ldb + schunk * 8;

    // swizzled ds_read chunk offset (row&7 == m16&7 for all frag rows):
    const int cswz = (quad ^ (m16 & 7)) * 8;    // ks=1 -> cswz ^ 32
    const int arow = wrq * 32 + m16;
    const int brow = wcq * 64 + m16;

    short8 a0[2][2], a1[2][2], bq[2][4];        // [ks][mi] / [ks][ni]
    f32x4 acc[2][2][2][4];                      // [qr][qc][mi][ni]
    #pragma unroll
    for (int i = 0; i < 2; i++)
        #pragma unroll
        for (int j = 0; j < 2; j++)
            #pragma unroll
            for (int mi = 0; mi < 2; mi++)
                #pragma unroll
                for (int ni = 0; ni < 4; ni++)
                    acc[i][j][mi][ni] = (f32x4){0.f, 0.f, 0.f, 0.f};

    auto STAGE_A = [&](int buf, int h, int toff) {
        u16* l = (u16*)lds + buf * 32768 + h * 8192 + wave * 512;
        const u16* g = aP + (long)(h * 128) * lda + toff;
        gld16(l, g);
        gld16(l + 4096, g + (long)64 * lda);
    };
    auto STAGE_B = [&](int buf, int h, int toff) {
        u16* l = (u16*)lds + buf * 32768 + 16384 + h * 8192 + wave * 512;
        const u16* g = bP + (long)(h * 128) * ldb + toff;
        gld16(l, g);
        gld16(l + 4096, g + (long)64 * ldb);
    };
    auto RDA = [&](short8 (&d)[2][2], int buf, int qr) {
        const u16* p = (const u16*)lds + buf * 32768 + qr * 8192 + arow * 64;
        d[0][0] = *(const short8*)(p + cswz);
        d[0][1] = *(const short8*)(p + 1024 + cswz);
        d[1][0] = *(const short8*)(p + (cswz ^ 32));
        d[1][1] = *(const short8*)(p + 1024 + (cswz ^ 32));
    };
    auto RDB = [&](int buf, int qc) {
        const u16* p = (const u16*)lds + buf * 32768 + 16384 + qc * 8192 + brow * 64;
        #pragma unroll
        for (int ks = 0; ks < 2; ks++)
            #pragma unroll
            for (int ni = 0; ni < 4; ni++)
                bq[ks][ni] = *(const short8*)(p + ni * 1024 + (cswz ^ (ks * 32)));
    };
    auto MMA = [&](f32x4 (&c)[2][4], const short8 (&a)[2][2]) {
        __builtin_amdgcn_s_setprio(1);
        #pragma unroll
        for (int ks = 0; ks < 2; ks++)
            #pragma unroll
            for (int mi = 0; mi < 2; mi++)
                #pragma unroll
                for (int ni = 0; ni < 4; ni++)
                    c[mi][ni] = __builtin_amdgcn_mfma_f32_16x16x32_bf16(
                        a[ks][mi], bq[ks][ni], c[mi][ni], 0, 0, 0);
        __builtin_amdgcn_s_setprio(0);
    };

    const int nt = K >> 6;        // 64-wide K-tiles (nt even, >= 4)
    const int niter = nt >> 1;

    // prologue: tile 0 fully + tile 1's B0,A1; drain once; enter steady state.
    STAGE_B(0, 0, 0); STAGE_A(0, 1, 0); STAGE_A(0, 0, 0); STAGE_B(0, 1, 0);
    STAGE_B(1, 0, 64); STAGE_A(1, 1, 64);
    asm volatile("s_waitcnt vmcnt(0)");
    __builtin_amdgcn_sched_barrier(0);
    __builtin_amdgcn_s_barrier();

    // 8 phases per iteration; stage targets per iteration j (tiles 2j,2j+1):
    //   p1:buf1.A0(+64) p2:buf1.B1(+64) p3:buf0.B0(+128) p4:buf0.A1(+128)
    //   p5:buf0.A0(+128) p6:buf0.B1(+128) p7:buf1.B0(+192) p8:buf1.A1(+192)
    // vmcnt(4) at p4 covers p1,p2 (read at p5/p7); at p8 covers p3..p6
    // (read at next p1..p4). Last main iteration j=niter-2 has t3=nt-1: in
    // range, so no clamps anywhere in the main loop.
    #pragma unroll 1
    for (int j = 0; j < niter - 1; ++j) {
        // ---- p1: T0.q(0,0) ----
        RDA(a0, 0, 0); RDB(0, 0);
        STAGE_A(1, 0, 64);
        asm volatile("s_waitcnt lgkmcnt(8)");
        __builtin_amdgcn_s_barrier();
        MMA(acc[0][0], a0);
        __builtin_amdgcn_s_barrier();
        // ---- p2: T0.q(1,0) ----
        RDA(a1, 0, 1);
        STAGE_B(1, 1, 64);
        __builtin_amdgcn_s_barrier();
        MMA(acc[1][0], a1);
        __builtin_amdgcn_s_barrier();
        // ---- p3: T0.q(1,1) ----
        RDB(0, 1);
        STAGE_B(0, 0, 128);
        __builtin_amdgcn_s_barrier();
        MMA(acc[1][1], a1);
        __builtin_amdgcn_s_barrier();
        // ---- p4: T0.q(0,1)  (a0, bq held in regs) ----
        STAGE_A(0, 1, 128);
        __builtin_amdgcn_s_barrier();
        MMA(acc[0][1], a0);
        asm volatile("s_waitcnt vmcnt(4)");
        __builtin_amdgcn_sched_barrier(0);
        __builtin_amdgcn_s_barrier();
        __builtin_amdgcn_sched_barrier(0);
        // ---- p5: T1.q(0,0) ----
        RDA(a0, 1, 0); RDB(1, 0);
        STAGE_A(0, 0, 128);
        asm volatile("s_waitcnt lgkmcnt(8)");
        __builtin_amdgcn_s_barrier();
        MMA(acc[0][0], a0);
        __builtin_amdgcn_s_barrier();
        // ---- p6: T1.q(1,0) ----
        RDA(a1, 1, 1);
        STAGE_B(0, 1, 128);
        __builtin_amdgcn_s_barrier();
        MMA(acc[1][0], a1);
        __builtin_amdgcn_s_barrier();
        // ---- p7: T1.q(1,1) ----
        RDB(1, 1);
        STAGE_B(1, 0, 192);
        __builtin_amdgcn_s_barrier();
        MMA(acc[1][1], a1);
        __builtin_amdgcn_s_barrier();
        // ---- p8: T1.q(0,1) ----
        STAGE_A(1, 1, 192);
        __builtin_amdgcn_s_barrier();
        MMA(acc[0][1], a0);
        asm volatile("s_waitcnt vmcnt(4)");
        __builtin_amdgcn_sched_barrier(0);
        __builtin_amdgcn_s_barrier();
        __builtin_amdgcn_sched_barrier(0);

        aP += 128; bP += 128;
    }

    // peeled final iteration (tiles nt-2, nt-1): p1/p2 stage real buf1 data
    // (tile nt-1); p3..p8 are dead restages of tile nt-1 into units whose
    // last ds_read completed >=1 barrier earlier (same safety as main loop).
    {
        // p1
        RDA(a0, 0, 0); RDB(0, 0);
        STAGE_A(1, 0, 64);
        asm volatile("s_waitcnt lgkmcnt(8)");
        __builtin_amdgcn_s_barrier();
        MMA(acc[0][0], a0);
        __builtin_amdgcn_s_barrier();
        // p2
        RDA(a1, 0, 1);
        STAGE_B(1, 1, 64);
        __builtin_amdgcn_s_barrier();
        MMA(acc[1][0], a1);
        __builtin_amdgcn_s_barrier();
        // p3
        RDB(0, 1);
        STAGE_B(0, 0, 64);
        __builtin_amdgcn_s_barrier();
        MMA(acc[1][1], a1);
        __builtin_amdgcn_s_barrier();
        // p4
        STAGE_A(0, 1, 64);
        __builtin_amdgcn_s_barrier();
        MMA(acc[0][1], a0);
        asm volatile("s_waitcnt vmcnt(4)");
        __builtin_amdgcn_sched_barrier(0);
        __builtin_amdgcn_s_barrier();
        __builtin_amdgcn_sched_barrier(0);
        // p5
        RDA(a0, 1, 0); RDB(1, 0);
        STAGE_A(0, 0, 64);
        asm volatile("s_waitcnt lgkmcnt(8)");
        __builtin_amdgcn_s_barrier();
        MMA(acc[0][0], a0);
        __builtin_amdgcn_s_barrier();
        // p6
        RDA(a1, 1, 1);
        STAGE_B(0, 1, 64);
        __builtin_amdgcn_s_barrier();
        MMA(acc[1][0], a1);
        __builtin_amdgcn_s_barrier();
        // p7
        RDB(1, 1);
        STAGE_B(1, 0, 64);
        __builtin_amdgcn_s_barrier();
        MMA(acc[1][1], a1);
        __builtin_amdgcn_s_barrier();
        // p8
        STAGE_A(1, 1, 64);
        __builtin_amdgcn_s_barrier();
        MMA(acc[0][1], a0);
    }

    // D mapping per 16x16 frag: col = lane&15, row = quad*4 + r.
    #pragma unroll
    for (int qr = 0; qr < 2; qr++) {
        const long row0 = m0 + qr * 128 + wrq * 32 + quad * 4;
        #pragma unroll
        for (int qc = 0; qc < 2; qc++) {
            #pragma unroll
            for (int ni = 0; ni < 4; ni++) {
                const long col = n0 + qc * 128 + wcq * 64 + ni * 16 + m16;
                if (EPI == 0) {
                    u16* C = (u16*)Cp + (long)b * cBatch;
                    const float bv = bias ? bias[col] : 0.f;
                    #pragma unroll
                    for (int mi = 0; mi < 2; mi++)
                        #pragma unroll
                        for (int r = 0; r < 4; r++)
                            C[(row0 + mi * 16 + r) * ldc + col] =
                                f2bf(acc[qr][qc][mi][ni][r] + bv);
                } else if (EPI == 1) {
                    u16* C = (u16*)Cp + (long)b * cBatch;
                    #pragma unroll
                    for (int mi = 0; mi < 2; mi++)
                        #pragma unroll
                        for (int r = 0; r < 4; r++)
                            C[(row0 + mi * 16 + r) * ldc + col] =
                                f2bf(acc[qr][qc][mi][ni][r] * scale);
                } else {
                    float* C = (float*)Cp + (long)b * cBatch;
                    const float bv = bias ? bias[col] : 0.f;
                    #pragma unroll
                    for (int mi = 0; mi < 2; mi++)
                        #pragma unroll
                        for (int r = 0; r < 4; r++)
                            C[(row0 + mi * 16 + r) * ldc + col] =
                                acc[qr][qc][mi][ni][r] + bv;
                }
            }
        }
    }
}

// in-place masked row softmax over 2048 bf16 (f32 math). 1 block per row.
__global__ __launch_bounds__(256) void softmax2048(u16* __restrict__ S,
                                                   const int* __restrict__ mask) {
    const long row = blockIdx.x;
    u16* p = S + row * SEQ;
    const int* mrow = mask + row * SEQ;
    const int tid = threadIdx.x;

    short8 v = *(const short8*)(p + tid * 8);
    uint4 mw0 = *(const uint4*)(mrow + tid * 8);
    uint4 mw1 = *(const uint4*)(mrow + tid * 8 + 4);
    const unsigned int* mwv = (const unsigned int*)&mw0;

    float f[8];
    #pragma unroll
    for (int j = 0; j < 8; j++) {
        const unsigned int mv = (j < 4) ? mwv[j] : ((const unsigned int*)&mw1)[j - 4];
        f[j] = (mv == 0u) ? 1e-10f : bf2f((u16)v[j]);
    }

    float m = f[0];
    #pragma unroll
    for (int j = 1; j < 8; j++) m = fmaxf(m, f[j]);
    #pragma unroll
    for (int i = 1; i < 64; i <<= 1) m = fmaxf(m, __shfl_xor(m, i));

    __shared__ float redm[4], reds[4];
    if ((tid & 63) == 0) redm[tid >> 6] = m;
    __syncthreads();
    m = fmaxf(fmaxf(redm[0], redm[1]), fmaxf(redm[2], redm[3]));

    float e[8], s = 0.f;
    #pragma unroll
    for (int j = 0; j < 8; j++) { e[j] = __expf(f[j] - m); s += e[j]; }
    #pragma unroll
    for (int i = 1; i < 64; i <<= 1) s += __shfl_xor(s, i);
    if ((tid & 63) == 0) reds[tid >> 6] = s;
    __syncthreads();
    s = reds[0] + reds[1] + reds[2] + reds[3];

    const float inv = 1.f / s;
    short8 o;
    #pragma unroll
    for (int j = 0; j < 8; j++) o[j] = (short)f2bf(e[j] * inv);
    *(short8*)(p + tid * 8) = o;
}

extern "C" void kernel_launch(void* const* d_in, const int* in_sizes, int n_in,
                              void* d_out, int out_size, void* d_ws, size_t ws_size,
                              hipStream_t stream) {
    const float* x    = (const float*)d_in[0];
    const int*   mask = (const int*)d_in[1];
    const float* Wqkv = (const float*)d_in[2];
    const float* bqkv = (const float*)d_in[3];
    const float* Wout = (const float*)d_in[4];
    const float* bout = (const float*)d_in[5];
    float* out = (float*)d_out;

    char* ws = (char*)d_ws;
    // ws layout, total 102,760,448 bytes:
    //   [0,        16777216) xh  bf16 [8192][1024]          (cvt -> K1)
    //   [16777216, 23068672) wqt bf16 [3072][1024]          (cvt -> K1)
    //   [0,        33554432) sc  bf16 [4][2048][2048]       (K2 -> K4; xh,wqt dead)
    //   [33554432, 35651584) wot bf16 [1024][1024]          (cvt -> K5)
    //   [35651584, 85983232) qkv bf16 [8192][3072]          (K1 -> K2)
    //   [35651584, 52428800) attn bf16 [8192][1024]         (K4 -> K5; qkv dead)
    //   [85983232,102760448) vt  bf16 [4][1024][2048]       (transpose_v -> K4)
    u16* xh   = (u16*)(ws + 0);
    u16* wqt  = (u16*)(ws + 16777216);
    u16* sc   = (u16*)(ws + 0);
    u16* wot  = (u16*)(ws + 33554432);
    u16* qkv  = (u16*)(ws + 35651584);
    u16* attn = (u16*)(ws + 35651584);
    u16* vt   = (u16*)(ws + 85983232);

    cvt_bf16<<<4096, 256, 0, stream>>>(x, xh, 8388608);
    transpose_cvt<<<dim3(96, 32), 256, 0, stream>>>(Wqkv, wqt, 1024, 3072);
    transpose_cvt<<<dim3(32, 32), 256, 0, stream>>>(Wout, wot, 1024, 1024);

    // K1: qkv = x @ Wqkv + bqkv   (M=8192, N=3072, K=1024), bf16 out
    gemm256<0><<<dim3(12, 32, 1), 512, 0, stream>>>(
        xh, 1024, 0, wqt, 1024, 0, qkv, 3072, 0, bqkv, 1.f, 1024);

    // V slice -> vt [b][d][s]
    transpose_v<<<dim3(32, 64, NB), 256, 0, stream>>>(qkv, vt);

    // K2: sc[b] = (Q[b] @ K[b]^T)/32   (M=N=2048, K=1024), bf16 out
    gemm256<1><<<dim3(8, 8, NB), 512, 0, stream>>>(
        qkv, 3072, (long)SEQ * 3072, qkv + 1024, 3072, (long)SEQ * 3072,
        sc, SEQ, (long)SEQ * SEQ, nullptr, 0.03125f, 1024);

    // K3: masked softmax rows (mask==0 -> 1e-10, f32 math, bf16 storage)
    softmax2048<<<dim3(NB * SEQ), 256, 0, stream>>>(sc, mask);

    // K4: attn[b] = P[b] @ V[b]   (M=2048, N=1024, K=2048), bf16 out
    gemm256<0><<<dim3(4, 8, NB), 512, 0, stream>>>(
        sc, SEQ, (long)SEQ * SEQ, vt, SEQ, (long)1024 * SEQ,
        attn, 1024, (long)SEQ * 1024, nullptr, 1.f, 2048);

    // K5: out = attn @ Wout + bout   (M=8192, N=1024, K=1024), f32 out
    gemm256<2><<<dim3(4, 32, 1), 512, 0, stream>>>(
        attn, 1024, 0, wot, 1024, 0, out, 1024, 0, bout, 1.f, 1024);
}

// Round 4
// 330.382 us; speedup vs baseline: 1.1739x; 1.0554x over previous
//
#include <hip/hip_runtime.h>

// Self-attention forward. Inputs f32: x[4,2048,1024], Wqkv[1024,3072],
// bqkv[3072], Wout[1024,1024], bout[1024]; mask[4,2048,2048] int32.
// Output f32 [4,2048,1024].
//
// Round-10: launch-geometry fixes on top of the round-9 8-phase schedule.
//   - K4/K5 were 128-block launches (half the GPU idle at 1 block/CU).
//     New gemm256n128 (BM=256, BN=128, 96 KB LDS, 4-phase iteration with
//     the same per-phase mix and vmcnt discipline) -> 256-block grids.
//   - T1 bijective XCD swizzle in both GEMMs (nwg%8==0 for all launches).
//   - s_waitcnt vmcnt(0) before epilogues: dead-restage global_load_lds
//     outstanding at s_endpgm could write a reallocated workgroup's LDS.

typedef __attribute__((ext_vector_type(8))) short short8;
typedef __attribute__((ext_vector_type(4))) float f32x4;
typedef unsigned short u16;

#define SEQ 2048
#define NB 4

static __device__ __forceinline__ u16 f2bf(float f) {
    unsigned int u = __builtin_bit_cast(unsigned int, f);
    u += 0x7fffu + ((u >> 16) & 1u);   // RNE
    return (u16)(u >> 16);
}
static __device__ __forceinline__ float bf2f(u16 h) {
    unsigned int u = ((unsigned int)h) << 16;
    return __builtin_bit_cast(float, u);
}

// async global->LDS, 16 bytes/lane. LDS dest = wave-uniform base + lane*16.
static __device__ __forceinline__ void gld16(u16* l, const u16* g) {
    __builtin_amdgcn_global_load_lds(
        (__attribute__((address_space(1))) void*)(g),
        (__attribute__((address_space(3))) void*)(l),
        16, 0, 0);
}

// f32 -> bf16, 8 elems/thread.
__global__ __launch_bounds__(256) void cvt_bf16(const float* __restrict__ s,
                                                u16* __restrict__ d, long n) {
    long i = ((long)blockIdx.x * 256 + threadIdx.x) * 8;
    if (i >= n) return;
    f32x4 a = *(const f32x4*)(s + i);
    f32x4 b = *(const f32x4*)(s + i + 4);
    short8 o;
    o[0] = (short)f2bf(a.x); o[1] = (short)f2bf(a.y);
    o[2] = (short)f2bf(a.z); o[3] = (short)f2bf(a.w);
    o[4] = (short)f2bf(b.x); o[5] = (short)f2bf(b.y);
    o[6] = (short)f2bf(b.z); o[7] = (short)f2bf(b.w);
    *(short8*)(d + i) = o;
}

// f32 [R][C] -> bf16 [C][R] (transpose + convert), 32x32 LDS tiles.
__global__ __launch_bounds__(256) void transpose_cvt(const float* __restrict__ in,
                                                     u16* __restrict__ out,
                                                     int R, int C) {
    __shared__ float t[32][33];
    const int c0 = blockIdx.x * 32;
    const int r0 = blockIdx.y * 32;
    const int x = threadIdx.x & 31;
    const int y = (threadIdx.x >> 5) * 4;
    #pragma unroll
    for (int i = 0; i < 4; i++)
        t[y + i][x] = in[(long)(r0 + y + i) * C + c0 + x];
    __syncthreads();
    #pragma unroll
    for (int i = 0; i < 4; i++)
        out[(long)(c0 + y + i) * R + r0 + x] = f2bf(t[x][y + i]);
}

// V slice of qkv -> vt [b][1024 d][2048 s]. bf16 32x32 tile transpose.
__global__ __launch_bounds__(256) void transpose_v(const u16* __restrict__ qkv,
                                                   u16* __restrict__ vt) {
    __shared__ u16 t[32][33];
    const int b = blockIdx.z;
    const int s0 = blockIdx.y * 32;
    const int d0 = blockIdx.x * 32;
    const int x = threadIdx.x & 31;
    const int y = (threadIdx.x >> 5) * 4;
    const u16* src = qkv + (long)b * SEQ * 3072 + 2048;
    u16* dst = vt + (long)b * 1024 * SEQ;
    #pragma unroll
    for (int i = 0; i < 4; i++)
        t[y + i][x] = src[(long)(s0 + y + i) * 3072 + d0 + x];
    __syncthreads();
    #pragma unroll
    for (int i = 0; i < 4; i++)
        dst[(long)(d0 + y + i) * SEQ + s0 + x] = t[x][y + i];
}

// bijective XCD swizzle of the flat (y*gx+x) tile id; requires nwg%8==0.
static __device__ __forceinline__ int xcd_swz(int flat, int nwg) {
    return (flat & 7) * (nwg >> 3) + (flat >> 3);
}

// bf16 MFMA GEMM, 256x256 tile, 8-phase 2-buffer pipeline (round-9 schedule).
// C[m][n] = sum_k A[m][k] * Bt[n][k]   (Bt = B^T, [N][K] row-major).
// EPI 0: bf16 out + optional f32 bias.  EPI 1: bf16 out, *scale.
// EPI 2: f32 out + f32 bias.
// Requires: M,N multiples of 256; K multiple of 128; (gx*gy)%8==0.
template<int EPI>
__global__ __launch_bounds__(512, 2) void gemm256(
    const u16* __restrict__ Ap, long lda, long aBatch,
    const u16* __restrict__ Bp, long ldb, long bBatch,
    void* __restrict__ Cp, long ldc, long cBatch,
    const float* __restrict__ bias,
    float scale, int K)
{
    // 2 bufs x (A[256][64] + B[256][64]) bf16 = 2 x 64 KB = 128 KB.
    __shared__ __attribute__((aligned(16))) u16 lds[65536];

    const int tid  = threadIdx.x;
    const int lane = tid & 63;
    const int wave = tid >> 6;          // 0..7
    const int wrq  = wave >> 1;         // 0..3: 32-row band within quadrant
    const int wcq  = wave & 1;          // 0..1: 64-col band within quadrant
    const int m16  = lane & 15;
    const int quad = lane >> 4;
    const int b    = blockIdx.z;

    const int gx = gridDim.x;
    const int flat = xcd_swz(blockIdx.y * gx + blockIdx.x, gx * gridDim.y);
    const long m0  = (long)(flat / gx) * 256;
    const long n0  = (long)(flat % gx) * 256;

    const u16* A = Ap + (long)b * aBatch;
    const u16* B = Bp + (long)b * bBatch;

    // staging lane constants (inverse-swizzled global source):
    const int srow   = lane >> 3;
    const int schunk = (lane & 7) ^ srow;
    const u16* aP = A + (m0 + wave * 8 + srow) * lda + schunk * 8;
    const u16* bP = B + (n0 + wave * 8 + srow) * ldb + schunk * 8;

    // swizzled ds_read chunk offset (row&7 == m16&7 for all frag rows):
    const int cswz = (quad ^ (m16 & 7)) * 8;    // ks=1 -> cswz ^ 32
    const int arow = wrq * 32 + m16;
    const int brow = wcq * 64 + m16;

    short8 a0[2][2], a1[2][2], bq[2][4];        // [ks][mi] / [ks][ni]
    f32x4 acc[2][2][2][4];                      // [qr][qc][mi][ni]
    #pragma unroll
    for (int i = 0; i < 2; i++)
        #pragma unroll
        for (int j = 0; j < 2; j++)
            #pragma unroll
            for (int mi = 0; mi < 2; mi++)
                #pragma unroll
                for (int ni = 0; ni < 4; ni++)
                    acc[i][j][mi][ni] = (f32x4){0.f, 0.f, 0.f, 0.f};

    auto STAGE_A = [&](int buf, int h, int toff) {
        u16* l = (u16*)lds + buf * 32768 + h * 8192 + wave * 512;
        const u16* g = aP + (long)(h * 128) * lda + toff;
        gld16(l, g);
        gld16(l + 4096, g + (long)64 * lda);
    };
    auto STAGE_B = [&](int buf, int h, int toff) {
        u16* l = (u16*)lds + buf * 32768 + 16384 + h * 8192 + wave * 512;
        const u16* g = bP + (long)(h * 128) * ldb + toff;
        gld16(l, g);
        gld16(l + 4096, g + (long)64 * ldb);
    };
    auto RDA = [&](short8 (&d)[2][2], int buf, int qr) {
        const u16* p = (const u16*)lds + buf * 32768 + qr * 8192 + arow * 64;
        d[0][0] = *(const short8*)(p + cswz);
        d[0][1] = *(const short8*)(p + 1024 + cswz);
        d[1][0] = *(const short8*)(p + (cswz ^ 32));
        d[1][1] = *(const short8*)(p + 1024 + (cswz ^ 32));
    };
    auto RDB = [&](int buf, int qc) {
        const u16* p = (const u16*)lds + buf * 32768 + 16384 + qc * 8192 + brow * 64;
        #pragma unroll
        for (int ks = 0; ks < 2; ks++)
            #pragma unroll
            for (int ni = 0; ni < 4; ni++)
                bq[ks][ni] = *(const short8*)(p + ni * 1024 + (cswz ^ (ks * 32)));
    };
    auto MMA = [&](f32x4 (&c)[2][4], const short8 (&a)[2][2]) {
        __builtin_amdgcn_s_setprio(1);
        #pragma unroll
        for (int ks = 0; ks < 2; ks++)
            #pragma unroll
            for (int mi = 0; mi < 2; mi++)
                #pragma unroll
                for (int ni = 0; ni < 4; ni++)
                    c[mi][ni] = __builtin_amdgcn_mfma_f32_16x16x32_bf16(
                        a[ks][mi], bq[ks][ni], c[mi][ni], 0, 0, 0);
        __builtin_amdgcn_s_setprio(0);
    };

    const int nt = K >> 6;        // 64-wide K-tiles (nt even, >= 4)
    const int niter = nt >> 1;

    STAGE_B(0, 0, 0); STAGE_A(0, 1, 0); STAGE_A(0, 0, 0); STAGE_B(0, 1, 0);
    STAGE_B(1, 0, 64); STAGE_A(1, 1, 64);
    asm volatile("s_waitcnt vmcnt(0)");
    __builtin_amdgcn_sched_barrier(0);
    __builtin_amdgcn_s_barrier();

    #pragma unroll 1
    for (int j = 0; j < niter - 1; ++j) {
        // p1
        RDA(a0, 0, 0); RDB(0, 0);
        STAGE_A(1, 0, 64);
        asm volatile("s_waitcnt lgkmcnt(8)");
        __builtin_amdgcn_s_barrier();
        MMA(acc[0][0], a0);
        __builtin_amdgcn_s_barrier();
        // p2
        RDA(a1, 0, 1);
        STAGE_B(1, 1, 64);
        __builtin_amdgcn_s_barrier();
        MMA(acc[1][0], a1);
        __builtin_amdgcn_s_barrier();
        // p3
        RDB(0, 1);
        STAGE_B(0, 0, 128);
        __builtin_amdgcn_s_barrier();
        MMA(acc[1][1], a1);
        __builtin_amdgcn_s_barrier();
        // p4
        STAGE_A(0, 1, 128);
        __builtin_amdgcn_s_barrier();
        MMA(acc[0][1], a0);
        asm volatile("s_waitcnt vmcnt(4)");
        __builtin_amdgcn_sched_barrier(0);
        __builtin_amdgcn_s_barrier();
        __builtin_amdgcn_sched_barrier(0);
        // p5
        RDA(a0, 1, 0); RDB(1, 0);
        STAGE_A(0, 0, 128);
        asm volatile("s_waitcnt lgkmcnt(8)");
        __builtin_amdgcn_s_barrier();
        MMA(acc[0][0], a0);
        __builtin_amdgcn_s_barrier();
        // p6
        RDA(a1, 1, 1);
        STAGE_B(0, 1, 128);
        __builtin_amdgcn_s_barrier();
        MMA(acc[1][0], a1);
        __builtin_amdgcn_s_barrier();
        // p7
        RDB(1, 1);
        STAGE_B(1, 0, 192);
        __builtin_amdgcn_s_barrier();
        MMA(acc[1][1], a1);
        __builtin_amdgcn_s_barrier();
        // p8
        STAGE_A(1, 1, 192);
        __builtin_amdgcn_s_barrier();
        MMA(acc[0][1], a0);
        asm volatile("s_waitcnt vmcnt(4)");
        __builtin_amdgcn_sched_barrier(0);
        __builtin_amdgcn_s_barrier();
        __builtin_amdgcn_sched_barrier(0);

        aP += 128; bP += 128;
    }

    // peeled final iteration (tiles nt-2, nt-1); p3.. stages are dead.
    {
        RDA(a0, 0, 0); RDB(0, 0);
        STAGE_A(1, 0, 64);
        asm volatile("s_waitcnt lgkmcnt(8)");
        __builtin_amdgcn_s_barrier();
        MMA(acc[0][0], a0);
        __builtin_amdgcn_s_barrier();
        RDA(a1, 0, 1);
        STAGE_B(1, 1, 64);
        __builtin_amdgcn_s_barrier();
        MMA(acc[1][0], a1);
        __builtin_amdgcn_s_barrier();
        RDB(0, 1);
        STAGE_B(0, 0, 64);
        __builtin_amdgcn_s_barrier();
        MMA(acc[1][1], a1);
        __builtin_amdgcn_s_barrier();
        STAGE_A(0, 1, 64);
        __builtin_amdgcn_s_barrier();
        MMA(acc[0][1], a0);
        asm volatile("s_waitcnt vmcnt(4)");
        __builtin_amdgcn_sched_barrier(0);
        __builtin_amdgcn_s_barrier();
        __builtin_amdgcn_sched_barrier(0);
        RDA(a0, 1, 0); RDB(1, 0);
        STAGE_A(0, 0, 64);
        asm volatile("s_waitcnt lgkmcnt(8)");
        __builtin_amdgcn_s_barrier();
        MMA(acc[0][0], a0);
        __builtin_amdgcn_s_barrier();
        RDA(a1, 1, 1);
        STAGE_B(0, 1, 64);
        __builtin_amdgcn_s_barrier();
        MMA(acc[1][0], a1);
        __builtin_amdgcn_s_barrier();
        RDB(1, 1);
        STAGE_B(1, 0, 64);
        __builtin_amdgcn_s_barrier();
        MMA(acc[1][1], a1);
        __builtin_amdgcn_s_barrier();
        STAGE_A(1, 1, 64);
        __builtin_amdgcn_s_barrier();
        MMA(acc[0][1], a0);
    }

    // drain async LDS writes before epilogue/endpgm (LDS realloc hazard)
    asm volatile("s_waitcnt vmcnt(0)");

    // D mapping per 16x16 frag: col = lane&15, row = quad*4 + r.
    #pragma unroll
    for (int qr = 0; qr < 2; qr++) {
        const long row0 = m0 + qr * 128 + wrq * 32 + quad * 4;
        #pragma unroll
        for (int qc = 0; qc < 2; qc++) {
            #pragma unroll
            for (int ni = 0; ni < 4; ni++) {
                const long col = n0 + qc * 128 + wcq * 64 + ni * 16 + m16;
                if (EPI == 0) {
                    u16* C = (u16*)Cp + (long)b * cBatch;
                    const float bv = bias ? bias[col] : 0.f;
                    #pragma unroll
                    for (int mi = 0; mi < 2; mi++)
                        #pragma unroll
                        for (int r = 0; r < 4; r++)
                            C[(row0 + mi * 16 + r) * ldc + col] =
                                f2bf(acc[qr][qc][mi][ni][r] + bv);
                } else if (EPI == 1) {
                    u16* C = (u16*)Cp + (long)b * cBatch;
                    #pragma unroll
                    for (int mi = 0; mi < 2; mi++)
                        #pragma unroll
                        for (int r = 0; r < 4; r++)
                            C[(row0 + mi * 16 + r) * ldc + col] =
                                f2bf(acc[qr][qc][mi][ni][r] * scale);
                } else {
                    float* C = (float*)Cp + (long)b * cBatch;
                    const float bv = bias ? bias[col] : 0.f;
                    #pragma unroll
                    for (int mi = 0; mi < 2; mi++)
                        #pragma unroll
                        for (int r = 0; r < 4; r++)
                            C[(row0 + mi * 16 + r) * ldc + col] =
                                acc[qr][qc][mi][ni][r] + bv;
                }
            }
        }
    }
}

// bf16 MFMA GEMM, 256x128 tile, 4-phase 2-buffer pipeline.
// Same per-phase mix as gemm256 (16 MFMA, 2 barriers, counted vmcnt(4) at
// p2/p4). Per K-tile: 2 quadrant-phases (qr=0: rows 0-127, qr=1: 128-255);
// B frags read once at p1/p3 and held. Stage units/K-tile: A0,A1,B0.
// Stage plan per iter j (tiles 2j buf0, 2j+1 buf1):
//   p1: buf1.A1(2j+1)  p2: buf0.A0,B0(2j+2)  p3: buf0.A1(2j+2)
//   p4: buf1.A0,B0(2j+3)
// vmcnt(4) at p2-end covers prev-p4 + p1 (read p3/p4); at p4-end covers
// p2,p3 (read next p1/p2). Overwrite safety: every unit restaged >=1
// barrier after its last read. Requires: M%256==0, N%128==0, K%128==0,
// (gx*gy)%8==0.
template<int EPI>
__global__ __launch_bounds__(512, 2) void gemm256n128(
    const u16* __restrict__ Ap, long lda, long aBatch,
    const u16* __restrict__ Bp, long ldb, long bBatch,
    void* __restrict__ Cp, long ldc, long cBatch,
    const float* __restrict__ bias,
    float scale, int K)
{
    // 2 bufs x (A[256][64] + B[128][64]) bf16 = 2 x 48 KB = 96 KB.
    // u16 offsets: buf*24576; A unit h at h*8192; B at 16384.
    __shared__ __attribute__((aligned(16))) u16 lds[49152];

    const int tid  = threadIdx.x;
    const int lane = tid & 63;
    const int wave = tid >> 6;          // 0..7
    const int wrq  = wave >> 1;         // 0..3: 32-row band within quadrant
    const int wcq  = wave & 1;          // 0..1: 64-col band within 128 cols
    const int m16  = lane & 15;
    const int quad = lane >> 4;
    const int b    = blockIdx.z;

    const int gx = gridDim.x;
    const int flat = xcd_swz(blockIdx.y * gx + blockIdx.x, gx * gridDim.y);
    const long m0  = (long)(flat / gx) * 256;
    const long n0  = (long)(flat % gx) * 128;

    const u16* A = Ap + (long)b * aBatch;
    const u16* B = Bp + (long)b * bBatch;

    const int srow   = lane >> 3;
    const int schunk = (lane & 7) ^ srow;
    const u16* aP = A + (m0 + wave * 8 + srow) * lda + schunk * 8;
    const u16* bP = B + (n0 + wave * 8 + srow) * ldb + schunk * 8;

    const int cswz = (quad ^ (m16 & 7)) * 8;
    const int arow = wrq * 32 + m16;
    const int brow = wcq * 64 + m16;

    short8 af[2][2], bq[2][4];          // [ks][mi] / [ks][ni]
    f32x4 acc[2][2][4];                 // [qr][mi][ni]
    #pragma unroll
    for (int qr = 0; qr < 2; qr++)
        #pragma unroll
        for (int mi = 0; mi < 2; mi++)
            #pragma unroll
            for (int ni = 0; ni < 4; ni++)
                acc[qr][mi][ni] = (f32x4){0.f, 0.f, 0.f, 0.f};

    auto STAGE_A = [&](int buf, int h, int toff) {
        u16* l = (u16*)lds + buf * 24576 + h * 8192 + wave * 512;
        const u16* g = aP + (long)(h * 128) * lda + toff;
        gld16(l, g);
        gld16(l + 4096, g + (long)64 * lda);
    };
    auto STAGE_B = [&](int buf, int toff) {
        u16* l = (u16*)lds + buf * 24576 + 16384 + wave * 512;
        const u16* g = bP + toff;
        gld16(l, g);
        gld16(l + 4096, g + (long)64 * ldb);
    };
    auto RDA = [&](int buf, int qr) {
        const u16* p = (const u16*)lds + buf * 24576 + qr * 8192 + arow * 64;
        af[0][0] = *(const short8*)(p + cswz);
        af[0][1] = *(const short8*)(p + 1024 + cswz);
        af[1][0] = *(const short8*)(p + (cswz ^ 32));
        af[1][1] = *(const short8*)(p + 1024 + (cswz ^ 32));
    };
    auto RDB = [&](int buf) {
        const u16* p = (const u16*)lds + buf * 24576 + 16384 + brow * 64;
        #pragma unroll
        for (int ks = 0; ks < 2; ks++)
            #pragma unroll
            for (int ni = 0; ni < 4; ni++)
                bq[ks][ni] = *(const short8*)(p + ni * 1024 + (cswz ^ (ks * 32)));
    };
    auto MMA = [&](f32x4 (&c)[2][4]) {
        __builtin_amdgcn_s_setprio(1);
        #pragma unroll
        for (int ks = 0; ks < 2; ks++)
            #pragma unroll
            for (int mi = 0; mi < 2; mi++)
                #pragma unroll
                for (int ni = 0; ni < 4; ni++)
                    c[mi][ni] = __builtin_amdgcn_mfma_f32_16x16x32_bf16(
                        af[ks][mi], bq[ks][ni], c[mi][ni], 0, 0, 0);
        __builtin_amdgcn_s_setprio(0);
    };

    const int nt = K >> 6;
    const int niter = nt >> 1;

    // prologue: buf0{A0,B0,A1}(t0), buf1{A0,B0}(t1); drain; steady state.
    STAGE_A(0, 0, 0); STAGE_B(0, 0); STAGE_A(0, 1, 0);
    STAGE_A(1, 0, 64); STAGE_B(1, 64);
    asm volatile("s_waitcnt vmcnt(0)");
    __builtin_amdgcn_sched_barrier(0);
    __builtin_amdgcn_s_barrier();

    #pragma unroll 1
    for (int j = 0; j < niter - 1; ++j) {
        // p1: T0.qr0
        RDA(0, 0); RDB(0);
        STAGE_A(1, 1, 64);
        asm volatile("s_waitcnt lgkmcnt(8)");
        __builtin_amdgcn_s_barrier();
        MMA(acc[0]);
        __builtin_amdgcn_s_barrier();
        // p2: T0.qr1
        RDA(0, 1);
        STAGE_A(0, 0, 128); STAGE_B(0, 128);
        __builtin_amdgcn_s_barrier();
        MMA(acc[1]);
        asm volatile("s_waitcnt vmcnt(4)");
        __builtin_amdgcn_sched_barrier(0);
        __builtin_amdgcn_s_barrier();
        __builtin_amdgcn_sched_barrier(0);
        // p3: T1.qr0
        RDA(1, 0); RDB(1);
        STAGE_A(0, 1, 128);
        asm volatile("s_waitcnt lgkmcnt(8)");
        __builtin_amdgcn_s_barrier();
        MMA(acc[0]);
        __builtin_amdgcn_s_barrier();
        // p4: T1.qr1
        RDA(1, 1);
        STAGE_A(1, 0, 192); STAGE_B(1, 192);
        __builtin_amdgcn_s_barrier();
        MMA(acc[1]);
        asm volatile("s_waitcnt vmcnt(4)");
        __builtin_amdgcn_sched_barrier(0);
        __builtin_amdgcn_s_barrier();
        __builtin_amdgcn_sched_barrier(0);

        aP += 128; bP += 128;
    }

    // peeled final iteration (tiles nt-2 buf0, nt-1 buf1).
    {
        // p1 (STAGE is real: buf1.A1 = tile nt-1, read at p4)
        RDA(0, 0); RDB(0);
        STAGE_A(1, 1, 64);
        asm volatile("s_waitcnt lgkmcnt(8)");
        __builtin_amdgcn_s_barrier();
        MMA(acc[0]);
        __builtin_amdgcn_s_barrier();
        // p2 (dead restages)
        RDA(0, 1);
        STAGE_A(0, 0, 64); STAGE_B(0, 64);
        __builtin_amdgcn_s_barrier();
        MMA(acc[1]);
        asm volatile("s_waitcnt vmcnt(4)");
        __builtin_amdgcn_sched_barrier(0);
        __builtin_amdgcn_s_barrier();
        __builtin_amdgcn_sched_barrier(0);
        // p3 (dead)
        RDA(1, 0); RDB(1);
        STAGE_A(0, 1, 64);
        asm volatile("s_waitcnt lgkmcnt(8)");
        __builtin_amdgcn_s_barrier();
        MMA(acc[0]);
        __builtin_amdgcn_s_barrier();
        // p4 (dead)
        RDA(1, 1);
        STAGE_A(1, 0, 64); STAGE_B(1, 64);
        __builtin_amdgcn_s_barrier();
        MMA(acc[1]);
    }

    // drain async LDS writes before epilogue/endpgm (LDS realloc hazard)
    asm volatile("s_waitcnt vmcnt(0)");

    // D mapping per 16x16 frag: col = lane&15, row = quad*4 + r.
    #pragma unroll
    for (int qr = 0; qr < 2; qr++) {
        const long row0 = m0 + qr * 128 + wrq * 32 + quad * 4;
        #pragma unroll
        for (int ni = 0; ni < 4; ni++) {
            const long col = n0 + wcq * 64 + ni * 16 + m16;
            if (EPI == 0) {
                u16* C = (u16*)Cp + (long)b * cBatch;
                const float bv = bias ? bias[col] : 0.f;
                #pragma unroll
                for (int mi = 0; mi < 2; mi++)
                    #pragma unroll
                    for (int r = 0; r < 4; r++)
                        C[(row0 + mi * 16 + r) * ldc + col] =
                            f2bf(acc[qr][mi][ni][r] + bv);
            } else if (EPI == 1) {
                u16* C = (u16*)Cp + (long)b * cBatch;
                #pragma unroll
                for (int mi = 0; mi < 2; mi++)
                    #pragma unroll
                    for (int r = 0; r < 4; r++)
                        C[(row0 + mi * 16 + r) * ldc + col] =
                            f2bf(acc[qr][mi][ni][r] * scale);
            } else {
                float* C = (float*)Cp + (long)b * cBatch;
                const float bv = bias ? bias[col] : 0.f;
                #pragma unroll
                for (int mi = 0; mi < 2; mi++)
                    #pragma unroll
                    for (int r = 0; r < 4; r++)
                        C[(row0 + mi * 16 + r) * ldc + col] =
                            acc[qr][mi][ni][r] + bv;
            }
        }
    }
}

// in-place masked row softmax over 2048 bf16 (f32 math). 1 block per row.
__global__ __launch_bounds__(256) void softmax2048(u16* __restrict__ S,
                                                   const int* __restrict__ mask) {
    const long row = blockIdx.x;
    u16* p = S + row * SEQ;
    const int* mrow = mask + row * SEQ;
    const int tid = threadIdx.x;

    short8 v = *(const short8*)(p + tid * 8);
    uint4 mw0 = *(const uint4*)(mrow + tid * 8);
    uint4 mw1 = *(const uint4*)(mrow + tid * 8 + 4);
    const unsigned int* mwv = (const unsigned int*)&mw0;

    float f[8];
    #pragma unroll
    for (int j = 0; j < 8; j++) {
        const unsigned int mv = (j < 4) ? mwv[j] : ((const unsigned int*)&mw1)[j - 4];
        f[j] = (mv == 0u) ? 1e-10f : bf2f((u16)v[j]);
    }

    float m = f[0];
    #pragma unroll
    for (int j = 1; j < 8; j++) m = fmaxf(m, f[j]);
    #pragma unroll
    for (int i = 1; i < 64; i <<= 1) m = fmaxf(m, __shfl_xor(m, i));

    __shared__ float redm[4], reds[4];
    if ((tid & 63) == 0) redm[tid >> 6] = m;
    __syncthreads();
    m = fmaxf(fmaxf(redm[0], redm[1]), fmaxf(redm[2], redm[3]));

    float e[8], s = 0.f;
    #pragma unroll
    for (int j = 0; j < 8; j++) { e[j] = __expf(f[j] - m); s += e[j]; }
    #pragma unroll
    for (int i = 1; i < 64; i <<= 1) s += __shfl_xor(s, i);
    if ((tid & 63) == 0) reds[tid >> 6] = s;
    __syncthreads();
    s = reds[0] + reds[1] + reds[2] + reds[3];

    const float inv = 1.f / s;
    short8 o;
    #pragma unroll
    for (int j = 0; j < 8; j++) o[j] = (short)f2bf(e[j] * inv);
    *(short8*)(p + tid * 8) = o;
}

extern "C" void kernel_launch(void* const* d_in, const int* in_sizes, int n_in,
                              void* d_out, int out_size, void* d_ws, size_t ws_size,
                              hipStream_t stream) {
    const float* x    = (const float*)d_in[0];
    const int*   mask = (const int*)d_in[1];
    const float* Wqkv = (const float*)d_in[2];
    const float* bqkv = (const float*)d_in[3];
    const float* Wout = (const float*)d_in[4];
    const float* bout = (const float*)d_in[5];
    float* out = (float*)d_out;

    char* ws = (char*)d_ws;
    // ws layout, total 102,760,448 bytes:
    //   [0,        16777216) xh  bf16 [8192][1024]          (cvt -> K1)
    //   [16777216, 23068672) wqt bf16 [3072][1024]          (cvt -> K1)
    //   [0,        33554432) sc  bf16 [4][2048][2048]       (K2 -> K4; xh,wqt dead)
    //   [33554432, 35651584) wot bf16 [1024][1024]          (cvt -> K5)
    //   [35651584, 85983232) qkv bf16 [8192][3072]          (K1 -> K2)
    //   [35651584, 52428800) attn bf16 [8192][1024]         (K4 -> K5; qkv dead)
    //   [85983232,102760448) vt  bf16 [4][1024][2048]       (transpose_v -> K4)
    u16* xh   = (u16*)(ws + 0);
    u16* wqt  = (u16*)(ws + 16777216);
    u16* sc   = (u16*)(ws + 0);
    u16* wot  = (u16*)(ws + 33554432);
    u16* qkv  = (u16*)(ws + 35651584);
    u16* attn = (u16*)(ws + 35651584);
    u16* vt   = (u16*)(ws + 85983232);

    cvt_bf16<<<4096, 256, 0, stream>>>(x, xh, 8388608);
    transpose_cvt<<<dim3(96, 32), 256, 0, stream>>>(Wqkv, wqt, 1024, 3072);
    transpose_cvt<<<dim3(32, 32), 256, 0, stream>>>(Wout, wot, 1024, 1024);

    // K1: qkv = x @ Wqkv + bqkv   (M=8192, N=3072, K=1024), bf16 out
    gemm256<0><<<dim3(12, 32, 1), 512, 0, stream>>>(
        xh, 1024, 0, wqt, 1024, 0, qkv, 3072, 0, bqkv, 1.f, 1024);

    // V slice -> vt [b][d][s]
    transpose_v<<<dim3(32, 64, NB), 256, 0, stream>>>(qkv, vt);

    // K2: sc[b] = (Q[b] @ K[b]^T)/32   (M=N=2048, K=1024), bf16 out
    gemm256<1><<<dim3(8, 8, NB), 512, 0, stream>>>(
        qkv, 3072, (long)SEQ * 3072, qkv + 1024, 3072, (long)SEQ * 3072,
        sc, SEQ, (long)SEQ * SEQ, nullptr, 0.03125f, 1024);

    // K3: masked softmax rows (mask==0 -> 1e-10, f32 math, bf16 storage)
    softmax2048<<<dim3(NB * SEQ), 256, 0, stream>>>(sc, mask);

    // K4: attn[b] = P[b] @ V[b]   (M=2048, N=1024, K=2048), bf16 out
    //     256x128 tile -> 8x8x4 = 256 blocks (was 128: half GPU idle)
    gemm256n128<0><<<dim3(8, 8, NB), 512, 0, stream>>>(
        sc, SEQ, (long)SEQ * SEQ, vt, SEQ, (long)1024 * SEQ,
        attn, 1024, (long)SEQ * 1024, nullptr, 1.f, 2048);

    // K5: out = attn @ Wout + bout   (M=8192, N=1024, K=1024), f32 out
    //     256x128 tile -> 8x32 = 256 blocks (was 128)
    gemm256n128<2><<<dim3(8, 32, 1), 512, 0, stream>>>(
        attn, 1024, 0, wot, 1024, 0, out, 1024, 0, bout, 1.f, 1024);
}

// Round 5
// 315.120 us; speedup vs baseline: 1.2307x; 1.0484x over previous
//
#include <hip/hip_runtime.h>

// Self-attention forward. Inputs f32: x[4,2048,1024], Wqkv[1024,3072],
// bqkv[3072], Wout[1024,1024], bout[1024]; mask[4,2048,2048] int32.
// Output f32 [4,2048,1024].
//
// Round-11:
//   - K1 moved to gemm256n128 (24x32 = 768 blocks = 3.0 exact dispatch
//     rounds). Round-4 counters: K1 on gemm256 was 384 blocks = 1.5 rounds
//     -> 2 rounds wall time (x1.33 tax, MfmaUtil 29% = 42% x 75%).
//   - Removed lgkmcnt(8) pre-barrier hints in both GEMMs: they stalled the
//     12-read phases ~150-250cy BEFORE the barrier; compiler-inserted
//     granular waits after the barrier are covered by the barrier wait.
//     (Safety: every ds_read is consumed by an MFMA in its own phase, so
//     regs are filled before the phase-end barrier; restages >=1 barrier
//     later.)

typedef __attribute__((ext_vector_type(8))) short short8;
typedef __attribute__((ext_vector_type(4))) float f32x4;
typedef unsigned short u16;

#define SEQ 2048
#define NB 4

static __device__ __forceinline__ u16 f2bf(float f) {
    unsigned int u = __builtin_bit_cast(unsigned int, f);
    u += 0x7fffu + ((u >> 16) & 1u);   // RNE
    return (u16)(u >> 16);
}
static __device__ __forceinline__ float bf2f(u16 h) {
    unsigned int u = ((unsigned int)h) << 16;
    return __builtin_bit_cast(float, u);
}

// async global->LDS, 16 bytes/lane. LDS dest = wave-uniform base + lane*16.
static __device__ __forceinline__ void gld16(u16* l, const u16* g) {
    __builtin_amdgcn_global_load_lds(
        (__attribute__((address_space(1))) void*)(g),
        (__attribute__((address_space(3))) void*)(l),
        16, 0, 0);
}

// f32 -> bf16, 8 elems/thread.
__global__ __launch_bounds__(256) void cvt_bf16(const float* __restrict__ s,
                                                u16* __restrict__ d, long n) {
    long i = ((long)blockIdx.x * 256 + threadIdx.x) * 8;
    if (i >= n) return;
    f32x4 a = *(const f32x4*)(s + i);
    f32x4 b = *(const f32x4*)(s + i + 4);
    short8 o;
    o[0] = (short)f2bf(a.x); o[1] = (short)f2bf(a.y);
    o[2] = (short)f2bf(a.z); o[3] = (short)f2bf(a.w);
    o[4] = (short)f2bf(b.x); o[5] = (short)f2bf(b.y);
    o[6] = (short)f2bf(b.z); o[7] = (short)f2bf(b.w);
    *(short8*)(d + i) = o;
}

// f32 [R][C] -> bf16 [C][R] (transpose + convert), 32x32 LDS tiles.
__global__ __launch_bounds__(256) void transpose_cvt(const float* __restrict__ in,
                                                     u16* __restrict__ out,
                                                     int R, int C) {
    __shared__ float t[32][33];
    const int c0 = blockIdx.x * 32;
    const int r0 = blockIdx.y * 32;
    const int x = threadIdx.x & 31;
    const int y = (threadIdx.x >> 5) * 4;
    #pragma unroll
    for (int i = 0; i < 4; i++)
        t[y + i][x] = in[(long)(r0 + y + i) * C + c0 + x];
    __syncthreads();
    #pragma unroll
    for (int i = 0; i < 4; i++)
        out[(long)(c0 + y + i) * R + r0 + x] = f2bf(t[x][y + i]);
}

// V slice of qkv -> vt [b][1024 d][2048 s]. bf16 32x32 tile transpose.
__global__ __launch_bounds__(256) void transpose_v(const u16* __restrict__ qkv,
                                                   u16* __restrict__ vt) {
    __shared__ u16 t[32][33];
    const int b = blockIdx.z;
    const int s0 = blockIdx.y * 32;
    const int d0 = blockIdx.x * 32;
    const int x = threadIdx.x & 31;
    const int y = (threadIdx.x >> 5) * 4;
    const u16* src = qkv + (long)b * SEQ * 3072 + 2048;
    u16* dst = vt + (long)b * 1024 * SEQ;
    #pragma unroll
    for (int i = 0; i < 4; i++)
        t[y + i][x] = src[(long)(s0 + y + i) * 3072 + d0 + x];
    __syncthreads();
    #pragma unroll
    for (int i = 0; i < 4; i++)
        dst[(long)(d0 + y + i) * SEQ + s0 + x] = t[x][y + i];
}

// bijective XCD swizzle of the flat (y*gx+x) tile id; requires nwg%8==0.
static __device__ __forceinline__ int xcd_swz(int flat, int nwg) {
    return (flat & 7) * (nwg >> 3) + (flat >> 3);
}

// bf16 MFMA GEMM, 256x256 tile, 8-phase 2-buffer pipeline (round-9 schedule).
// C[m][n] = sum_k A[m][k] * Bt[n][k]   (Bt = B^T, [N][K] row-major).
// EPI 0: bf16 out + optional f32 bias.  EPI 1: bf16 out, *scale.
// EPI 2: f32 out + f32 bias.
// Requires: M,N multiples of 256; K multiple of 128; (gx*gy)%8==0.
template<int EPI>
__global__ __launch_bounds__(512, 2) void gemm256(
    const u16* __restrict__ Ap, long lda, long aBatch,
    const u16* __restrict__ Bp, long ldb, long bBatch,
    void* __restrict__ Cp, long ldc, long cBatch,
    const float* __restrict__ bias,
    float scale, int K)
{
    // 2 bufs x (A[256][64] + B[256][64]) bf16 = 2 x 64 KB = 128 KB.
    __shared__ __attribute__((aligned(16))) u16 lds[65536];

    const int tid  = threadIdx.x;
    const int lane = tid & 63;
    const int wave = tid >> 6;          // 0..7
    const int wrq  = wave >> 1;         // 0..3: 32-row band within quadrant
    const int wcq  = wave & 1;          // 0..1: 64-col band within quadrant
    const int m16  = lane & 15;
    const int quad = lane >> 4;
    const int b    = blockIdx.z;

    const int gx = gridDim.x;
    const int flat = xcd_swz(blockIdx.y * gx + blockIdx.x, gx * gridDim.y);
    const long m0  = (long)(flat / gx) * 256;
    const long n0  = (long)(flat % gx) * 256;

    const u16* A = Ap + (long)b * aBatch;
    const u16* B = Bp + (long)b * bBatch;

    // staging lane constants (inverse-swizzled global source):
    const int srow   = lane >> 3;
    const int schunk = (lane & 7) ^ srow;
    const u16* aP = A + (m0 + wave * 8 + srow) * lda + schunk * 8;
    const u16* bP = B + (n0 + wave * 8 + srow) * ldb + schunk * 8;

    // swizzled ds_read chunk offset (row&7 == m16&7 for all frag rows):
    const int cswz = (quad ^ (m16 & 7)) * 8;    // ks=1 -> cswz ^ 32
    const int arow = wrq * 32 + m16;
    const int brow = wcq * 64 + m16;

    short8 a0[2][2], a1[2][2], bq[2][4];        // [ks][mi] / [ks][ni]
    f32x4 acc[2][2][2][4];                      // [qr][qc][mi][ni]
    #pragma unroll
    for (int i = 0; i < 2; i++)
        #pragma unroll
        for (int j = 0; j < 2; j++)
            #pragma unroll
            for (int mi = 0; mi < 2; mi++)
                #pragma unroll
                for (int ni = 0; ni < 4; ni++)
                    acc[i][j][mi][ni] = (f32x4){0.f, 0.f, 0.f, 0.f};

    auto STAGE_A = [&](int buf, int h, int toff) {
        u16* l = (u16*)lds + buf * 32768 + h * 8192 + wave * 512;
        const u16* g = aP + (long)(h * 128) * lda + toff;
        gld16(l, g);
        gld16(l + 4096, g + (long)64 * lda);
    };
    auto STAGE_B = [&](int buf, int h, int toff) {
        u16* l = (u16*)lds + buf * 32768 + 16384 + h * 8192 + wave * 512;
        const u16* g = bP + (long)(h * 128) * ldb + toff;
        gld16(l, g);
        gld16(l + 4096, g + (long)64 * ldb);
    };
    auto RDA = [&](short8 (&d)[2][2], int buf, int qr) {
        const u16* p = (const u16*)lds + buf * 32768 + qr * 8192 + arow * 64;
        d[0][0] = *(const short8*)(p + cswz);
        d[0][1] = *(const short8*)(p + 1024 + cswz);
        d[1][0] = *(const short8*)(p + (cswz ^ 32));
        d[1][1] = *(const short8*)(p + 1024 + (cswz ^ 32));
    };
    auto RDB = [&](int buf, int qc) {
        const u16* p = (const u16*)lds + buf * 32768 + 16384 + qc * 8192 + brow * 64;
        #pragma unroll
        for (int ks = 0; ks < 2; ks++)
            #pragma unroll
            for (int ni = 0; ni < 4; ni++)
                bq[ks][ni] = *(const short8*)(p + ni * 1024 + (cswz ^ (ks * 32)));
    };
    auto MMA = [&](f32x4 (&c)[2][4], const short8 (&a)[2][2]) {
        __builtin_amdgcn_s_setprio(1);
        #pragma unroll
        for (int ks = 0; ks < 2; ks++)
            #pragma unroll
            for (int mi = 0; mi < 2; mi++)
                #pragma unroll
                for (int ni = 0; ni < 4; ni++)
                    c[mi][ni] = __builtin_amdgcn_mfma_f32_16x16x32_bf16(
                        a[ks][mi], bq[ks][ni], c[mi][ni], 0, 0, 0);
        __builtin_amdgcn_s_setprio(0);
    };

    const int nt = K >> 6;        // 64-wide K-tiles (nt even, >= 4)
    const int niter = nt >> 1;

    STAGE_B(0, 0, 0); STAGE_A(0, 1, 0); STAGE_A(0, 0, 0); STAGE_B(0, 1, 0);
    STAGE_B(1, 0, 64); STAGE_A(1, 1, 64);
    asm volatile("s_waitcnt vmcnt(0)");
    __builtin_amdgcn_sched_barrier(0);
    __builtin_amdgcn_s_barrier();

    #pragma unroll 1
    for (int j = 0; j < niter - 1; ++j) {
        // p1
        RDA(a0, 0, 0); RDB(0, 0);
        STAGE_A(1, 0, 64);
        __builtin_amdgcn_s_barrier();
        MMA(acc[0][0], a0);
        __builtin_amdgcn_s_barrier();
        // p2
        RDA(a1, 0, 1);
        STAGE_B(1, 1, 64);
        __builtin_amdgcn_s_barrier();
        MMA(acc[1][0], a1);
        __builtin_amdgcn_s_barrier();
        // p3
        RDB(0, 1);
        STAGE_B(0, 0, 128);
        __builtin_amdgcn_s_barrier();
        MMA(acc[1][1], a1);
        __builtin_amdgcn_s_barrier();
        // p4
        STAGE_A(0, 1, 128);
        __builtin_amdgcn_s_barrier();
        MMA(acc[0][1], a0);
        asm volatile("s_waitcnt vmcnt(4)");
        __builtin_amdgcn_sched_barrier(0);
        __builtin_amdgcn_s_barrier();
        __builtin_amdgcn_sched_barrier(0);
        // p5
        RDA(a0, 1, 0); RDB(1, 0);
        STAGE_A(0, 0, 128);
        __builtin_amdgcn_s_barrier();
        MMA(acc[0][0], a0);
        __builtin_amdgcn_s_barrier();
        // p6
        RDA(a1, 1, 1);
        STAGE_B(0, 1, 128);
        __builtin_amdgcn_s_barrier();
        MMA(acc[1][0], a1);
        __builtin_amdgcn_s_barrier();
        // p7
        RDB(1, 1);
        STAGE_B(1, 0, 192);
        __builtin_amdgcn_s_barrier();
        MMA(acc[1][1], a1);
        __builtin_amdgcn_s_barrier();
        // p8
        STAGE_A(1, 1, 192);
        __builtin_amdgcn_s_barrier();
        MMA(acc[0][1], a0);
        asm volatile("s_waitcnt vmcnt(4)");
        __builtin_amdgcn_sched_barrier(0);
        __builtin_amdgcn_s_barrier();
        __builtin_amdgcn_sched_barrier(0);

        aP += 128; bP += 128;
    }

    // peeled final iteration (tiles nt-2, nt-1); p3.. stages are dead.
    {
        RDA(a0, 0, 0); RDB(0, 0);
        STAGE_A(1, 0, 64);
        __builtin_amdgcn_s_barrier();
        MMA(acc[0][0], a0);
        __builtin_amdgcn_s_barrier();
        RDA(a1, 0, 1);
        STAGE_B(1, 1, 64);
        __builtin_amdgcn_s_barrier();
        MMA(acc[1][0], a1);
        __builtin_amdgcn_s_barrier();
        RDB(0, 1);
        STAGE_B(0, 0, 64);
        __builtin_amdgcn_s_barrier();
        MMA(acc[1][1], a1);
        __builtin_amdgcn_s_barrier();
        STAGE_A(0, 1, 64);
        __builtin_amdgcn_s_barrier();
        MMA(acc[0][1], a0);
        asm volatile("s_waitcnt vmcnt(4)");
        __builtin_amdgcn_sched_barrier(0);
        __builtin_amdgcn_s_barrier();
        __builtin_amdgcn_sched_barrier(0);
        RDA(a0, 1, 0); RDB(1, 0);
        STAGE_A(0, 0, 64);
        __builtin_amdgcn_s_barrier();
        MMA(acc[0][0], a0);
        __builtin_amdgcn_s_barrier();
        RDA(a1, 1, 1);
        STAGE_B(0, 1, 64);
        __builtin_amdgcn_s_barrier();
        MMA(acc[1][0], a1);
        __builtin_amdgcn_s_barrier();
        RDB(1, 1);
        STAGE_B(1, 0, 64);
        __builtin_amdgcn_s_barrier();
        MMA(acc[1][1], a1);
        __builtin_amdgcn_s_barrier();
        STAGE_A(1, 1, 64);
        __builtin_amdgcn_s_barrier();
        MMA(acc[0][1], a0);
    }

    // drain async LDS writes before epilogue/endpgm (LDS realloc hazard)
    asm volatile("s_waitcnt vmcnt(0)");

    // D mapping per 16x16 frag: col = lane&15, row = quad*4 + r.
    #pragma unroll
    for (int qr = 0; qr < 2; qr++) {
        const long row0 = m0 + qr * 128 + wrq * 32 + quad * 4;
        #pragma unroll
        for (int qc = 0; qc < 2; qc++) {
            #pragma unroll
            for (int ni = 0; ni < 4; ni++) {
                const long col = n0 + qc * 128 + wcq * 64 + ni * 16 + m16;
                if (EPI == 0) {
                    u16* C = (u16*)Cp + (long)b * cBatch;
                    const float bv = bias ? bias[col] : 0.f;
                    #pragma unroll
                    for (int mi = 0; mi < 2; mi++)
                        #pragma unroll
                        for (int r = 0; r < 4; r++)
                            C[(row0 + mi * 16 + r) * ldc + col] =
                                f2bf(acc[qr][qc][mi][ni][r] + bv);
                } else if (EPI == 1) {
                    u16* C = (u16*)Cp + (long)b * cBatch;
                    #pragma unroll
                    for (int mi = 0; mi < 2; mi++)
                        #pragma unroll
                        for (int r = 0; r < 4; r++)
                            C[(row0 + mi * 16 + r) * ldc + col] =
                                f2bf(acc[qr][qc][mi][ni][r] * scale);
                } else {
                    float* C = (float*)Cp + (long)b * cBatch;
                    const float bv = bias ? bias[col] : 0.f;
                    #pragma unroll
                    for (int mi = 0; mi < 2; mi++)
                        #pragma unroll
                        for (int r = 0; r < 4; r++)
                            C[(row0 + mi * 16 + r) * ldc + col] =
                                acc[qr][qc][mi][ni][r] + bv;
                }
            }
        }
    }
}

// bf16 MFMA GEMM, 256x128 tile, 4-phase 2-buffer pipeline.
// Same per-phase mix as gemm256 (16 MFMA, 2 barriers, counted vmcnt(4) at
// p2/p4). Per K-tile: 2 quadrant-phases (qr=0: rows 0-127, qr=1: 128-255);
// B frags read once at p1/p3 and held. Stage units/K-tile: A0,A1,B0.
// Stage plan per iter j (tiles 2j buf0, 2j+1 buf1):
//   p1: buf1.A1(2j+1)  p2: buf0.A0,B0(2j+2)  p3: buf0.A1(2j+2)
//   p4: buf1.A0,B0(2j+3)
// vmcnt(4) at p2-end covers prev-p4 + p1 (read p3/p4); at p4-end covers
// p2,p3 (read next p1/p2). Overwrite safety: every unit restaged >=1
// barrier after its last read. Requires: M%256==0, N%128==0, K%128==0,
// (gx*gy)%8==0.
template<int EPI>
__global__ __launch_bounds__(512, 2) void gemm256n128(
    const u16* __restrict__ Ap, long lda, long aBatch,
    const u16* __restrict__ Bp, long ldb, long bBatch,
    void* __restrict__ Cp, long ldc, long cBatch,
    const float* __restrict__ bias,
    float scale, int K)
{
    // 2 bufs x (A[256][64] + B[128][64]) bf16 = 2 x 48 KB = 96 KB.
    // u16 offsets: buf*24576; A unit h at h*8192; B at 16384.
    __shared__ __attribute__((aligned(16))) u16 lds[49152];

    const int tid  = threadIdx.x;
    const int lane = tid & 63;
    const int wave = tid >> 6;          // 0..7
    const int wrq  = wave >> 1;         // 0..3: 32-row band within quadrant
    const int wcq  = wave & 1;          // 0..1: 64-col band within 128 cols
    const int m16  = lane & 15;
    const int quad = lane >> 4;
    const int b    = blockIdx.z;

    const int gx = gridDim.x;
    const int flat = xcd_swz(blockIdx.y * gx + blockIdx.x, gx * gridDim.y);
    const long m0  = (long)(flat / gx) * 256;
    const long n0  = (long)(flat % gx) * 128;

    const u16* A = Ap + (long)b * aBatch;
    const u16* B = Bp + (long)b * bBatch;

    const int srow   = lane >> 3;
    const int schunk = (lane & 7) ^ srow;
    const u16* aP = A + (m0 + wave * 8 + srow) * lda + schunk * 8;
    const u16* bP = B + (n0 + wave * 8 + srow) * ldb + schunk * 8;

    const int cswz = (quad ^ (m16 & 7)) * 8;
    const int arow = wrq * 32 + m16;
    const int brow = wcq * 64 + m16;

    short8 af[2][2], bq[2][4];          // [ks][mi] / [ks][ni]
    f32x4 acc[2][2][4];                 // [qr][mi][ni]
    #pragma unroll
    for (int qr = 0; qr < 2; qr++)
        #pragma unroll
        for (int mi = 0; mi < 2; mi++)
            #pragma unroll
            for (int ni = 0; ni < 4; ni++)
                acc[qr][mi][ni] = (f32x4){0.f, 0.f, 0.f, 0.f};

    auto STAGE_A = [&](int buf, int h, int toff) {
        u16* l = (u16*)lds + buf * 24576 + h * 8192 + wave * 512;
        const u16* g = aP + (long)(h * 128) * lda + toff;
        gld16(l, g);
        gld16(l + 4096, g + (long)64 * lda);
    };
    auto STAGE_B = [&](int buf, int toff) {
        u16* l = (u16*)lds + buf * 24576 + 16384 + wave * 512;
        const u16* g = bP + toff;
        gld16(l, g);
        gld16(l + 4096, g + (long)64 * ldb);
    };
    auto RDA = [&](int buf, int qr) {
        const u16* p = (const u16*)lds + buf * 24576 + qr * 8192 + arow * 64;
        af[0][0] = *(const short8*)(p + cswz);
        af[0][1] = *(const short8*)(p + 1024 + cswz);
        af[1][0] = *(const short8*)(p + (cswz ^ 32));
        af[1][1] = *(const short8*)(p + 1024 + (cswz ^ 32));
    };
    auto RDB = [&](int buf) {
        const u16* p = (const u16*)lds + buf * 24576 + 16384 + brow * 64;
        #pragma unroll
        for (int ks = 0; ks < 2; ks++)
            #pragma unroll
            for (int ni = 0; ni < 4; ni++)
                bq[ks][ni] = *(const short8*)(p + ni * 1024 + (cswz ^ (ks * 32)));
    };
    auto MMA = [&](f32x4 (&c)[2][4]) {
        __builtin_amdgcn_s_setprio(1);
        #pragma unroll
        for (int ks = 0; ks < 2; ks++)
            #pragma unroll
            for (int mi = 0; mi < 2; mi++)
                #pragma unroll
                for (int ni = 0; ni < 4; ni++)
                    c[mi][ni] = __builtin_amdgcn_mfma_f32_16x16x32_bf16(
                        af[ks][mi], bq[ks][ni], c[mi][ni], 0, 0, 0);
        __builtin_amdgcn_s_setprio(0);
    };

    const int nt = K >> 6;
    const int niter = nt >> 1;

    // prologue: buf0{A0,B0,A1}(t0), buf1{A0,B0}(t1); drain; steady state.
    STAGE_A(0, 0, 0); STAGE_B(0, 0); STAGE_A(0, 1, 0);
    STAGE_A(1, 0, 64); STAGE_B(1, 64);
    asm volatile("s_waitcnt vmcnt(0)");
    __builtin_amdgcn_sched_barrier(0);
    __builtin_amdgcn_s_barrier();

    #pragma unroll 1
    for (int j = 0; j < niter - 1; ++j) {
        // p1: T0.qr0
        RDA(0, 0); RDB(0);
        STAGE_A(1, 1, 64);
        __builtin_amdgcn_s_barrier();
        MMA(acc[0]);
        __builtin_amdgcn_s_barrier();
        // p2: T0.qr1
        RDA(0, 1);
        STAGE_A(0, 0, 128); STAGE_B(0, 128);
        __builtin_amdgcn_s_barrier();
        MMA(acc[1]);
        asm volatile("s_waitcnt vmcnt(4)");
        __builtin_amdgcn_sched_barrier(0);
        __builtin_amdgcn_s_barrier();
        __builtin_amdgcn_sched_barrier(0);
        // p3: T1.qr0
        RDA(1, 0); RDB(1);
        STAGE_A(0, 1, 128);
        __builtin_amdgcn_s_barrier();
        MMA(acc[0]);
        __builtin_amdgcn_s_barrier();
        // p4: T1.qr1
        RDA(1, 1);
        STAGE_A(1, 0, 192); STAGE_B(1, 192);
        __builtin_amdgcn_s_barrier();
        MMA(acc[1]);
        asm volatile("s_waitcnt vmcnt(4)");
        __builtin_amdgcn_sched_barrier(0);
        __builtin_amdgcn_s_barrier();
        __builtin_amdgcn_sched_barrier(0);

        aP += 128; bP += 128;
    }

    // peeled final iteration (tiles nt-2 buf0, nt-1 buf1).
    {
        // p1 (STAGE is real: buf1.A1 = tile nt-1, read at p4)
        RDA(0, 0); RDB(0);
        STAGE_A(1, 1, 64);
        __builtin_amdgcn_s_barrier();
        MMA(acc[0]);
        __builtin_amdgcn_s_barrier();
        // p2 (dead restages)
        RDA(0, 1);
        STAGE_A(0, 0, 64); STAGE_B(0, 64);
        __builtin_amdgcn_s_barrier();
        MMA(acc[1]);
        asm volatile("s_waitcnt vmcnt(4)");
        __builtin_amdgcn_sched_barrier(0);
        __builtin_amdgcn_s_barrier();
        __builtin_amdgcn_sched_barrier(0);
        // p3 (dead)
        RDA(1, 0); RDB(1);
        STAGE_A(0, 1, 64);
        __builtin_amdgcn_s_barrier();
        MMA(acc[0]);
        __builtin_amdgcn_s_barrier();
        // p4 (dead)
        RDA(1, 1);
        STAGE_A(1, 0, 64); STAGE_B(1, 64);
        __builtin_amdgcn_s_barrier();
        MMA(acc[1]);
    }

    // drain async LDS writes before epilogue/endpgm (LDS realloc hazard)
    asm volatile("s_waitcnt vmcnt(0)");

    // D mapping per 16x16 frag: col = lane&15, row = quad*4 + r.
    #pragma unroll
    for (int qr = 0; qr < 2; qr++) {
        const long row0 = m0 + qr * 128 + wrq * 32 + quad * 4;
        #pragma unroll
        for (int ni = 0; ni < 4; ni++) {
            const long col = n0 + wcq * 64 + ni * 16 + m16;
            if (EPI == 0) {
                u16* C = (u16*)Cp + (long)b * cBatch;
                const float bv = bias ? bias[col] : 0.f;
                #pragma unroll
                for (int mi = 0; mi < 2; mi++)
                    #pragma unroll
                    for (int r = 0; r < 4; r++)
                        C[(row0 + mi * 16 + r) * ldc + col] =
                            f2bf(acc[qr][mi][ni][r] + bv);
            } else if (EPI == 1) {
                u16* C = (u16*)Cp + (long)b * cBatch;
                #pragma unroll
                for (int mi = 0; mi < 2; mi++)
                    #pragma unroll
                    for (int r = 0; r < 4; r++)
                        C[(row0 + mi * 16 + r) * ldc + col] =
                            f2bf(acc[qr][mi][ni][r] * scale);
            } else {
                float* C = (float*)Cp + (long)b * cBatch;
                const float bv = bias ? bias[col] : 0.f;
                #pragma unroll
                for (int mi = 0; mi < 2; mi++)
                    #pragma unroll
                    for (int r = 0; r < 4; r++)
                        C[(row0 + mi * 16 + r) * ldc + col] =
                            acc[qr][mi][ni][r] + bv;
            }
        }
    }
}

// in-place masked row softmax over 2048 bf16 (f32 math). 1 block per row.
__global__ __launch_bounds__(256) void softmax2048(u16* __restrict__ S,
                                                   const int* __restrict__ mask) {
    const long row = blockIdx.x;
    u16* p = S + row * SEQ;
    const int* mrow = mask + row * SEQ;
    const int tid = threadIdx.x;

    short8 v = *(const short8*)(p + tid * 8);
    uint4 mw0 = *(const uint4*)(mrow + tid * 8);
    uint4 mw1 = *(const uint4*)(mrow + tid * 8 + 4);
    const unsigned int* mwv = (const unsigned int*)&mw0;

    float f[8];
    #pragma unroll
    for (int j = 0; j < 8; j++) {
        const unsigned int mv = (j < 4) ? mwv[j] : ((const unsigned int*)&mw1)[j - 4];
        f[j] = (mv == 0u) ? 1e-10f : bf2f((u16)v[j]);
    }

    float m = f[0];
    #pragma unroll
    for (int j = 1; j < 8; j++) m = fmaxf(m, f[j]);
    #pragma unroll
    for (int i = 1; i < 64; i <<= 1) m = fmaxf(m, __shfl_xor(m, i));

    __shared__ float redm[4], reds[4];
    if ((tid & 63) == 0) redm[tid >> 6] = m;
    __syncthreads();
    m = fmaxf(fmaxf(redm[0], redm[1]), fmaxf(redm[2], redm[3]));

    float e[8], s = 0.f;
    #pragma unroll
    for (int j = 0; j < 8; j++) { e[j] = __expf(f[j] - m); s += e[j]; }
    #pragma unroll
    for (int i = 1; i < 64; i <<= 1) s += __shfl_xor(s, i);
    if ((tid & 63) == 0) reds[tid >> 6] = s;
    __syncthreads();
    s = reds[0] + reds[1] + reds[2] + reds[3];

    const float inv = 1.f / s;
    short8 o;
    #pragma unroll
    for (int j = 0; j < 8; j++) o[j] = (short)f2bf(e[j] * inv);
    *(short8*)(p + tid * 8) = o;
}

extern "C" void kernel_launch(void* const* d_in, const int* in_sizes, int n_in,
                              void* d_out, int out_size, void* d_ws, size_t ws_size,
                              hipStream_t stream) {
    const float* x    = (const float*)d_in[0];
    const int*   mask = (const int*)d_in[1];
    const float* Wqkv = (const float*)d_in[2];
    const float* bqkv = (const float*)d_in[3];
    const float* Wout = (const float*)d_in[4];
    const float* bout = (const float*)d_in[5];
    float* out = (float*)d_out;

    char* ws = (char*)d_ws;
    // ws layout, total 102,760,448 bytes:
    //   [0,        16777216) xh  bf16 [8192][1024]          (cvt -> K1)
    //   [16777216, 23068672) wqt bf16 [3072][1024]          (cvt -> K1)
    //   [0,        33554432) sc  bf16 [4][2048][2048]       (K2 -> K4; xh,wqt dead)
    //   [33554432, 35651584) wot bf16 [1024][1024]          (cvt -> K5)
    //   [35651584, 85983232) qkv bf16 [8192][3072]          (K1 -> K2)
    //   [35651584, 52428800) attn bf16 [8192][1024]         (K4 -> K5; qkv dead)
    //   [85983232,102760448) vt  bf16 [4][1024][2048]       (transpose_v -> K4)
    u16* xh   = (u16*)(ws + 0);
    u16* wqt  = (u16*)(ws + 16777216);
    u16* sc   = (u16*)(ws + 0);
    u16* wot  = (u16*)(ws + 33554432);
    u16* qkv  = (u16*)(ws + 35651584);
    u16* attn = (u16*)(ws + 35651584);
    u16* vt   = (u16*)(ws + 85983232);

    cvt_bf16<<<4096, 256, 0, stream>>>(x, xh, 8388608);
    transpose_cvt<<<dim3(96, 32), 256, 0, stream>>>(Wqkv, wqt, 1024, 3072);
    transpose_cvt<<<dim3(32, 32), 256, 0, stream>>>(Wout, wot, 1024, 1024);

    // K1: qkv = x @ Wqkv + bqkv   (M=8192, N=3072, K=1024), bf16 out
    //     256x128 tile -> 24x32 = 768 blocks = 3.0 exact rounds
    //     (was gemm256 384 blocks = 1.5 rounds -> 2 rounds wall time)
    gemm256n128<0><<<dim3(24, 32, 1), 512, 0, stream>>>(
        xh, 1024, 0, wqt, 1024, 0, qkv, 3072, 0, bqkv, 1.f, 1024);

    // V slice -> vt [b][d][s]
    transpose_v<<<dim3(32, 64, NB), 256, 0, stream>>>(qkv, vt);

    // K2: sc[b] = (Q[b] @ K[b]^T)/32   (M=N=2048, K=1024), bf16 out
    gemm256<1><<<dim3(8, 8, NB), 512, 0, stream>>>(
        qkv, 3072, (long)SEQ * 3072, qkv + 1024, 3072, (long)SEQ * 3072,
        sc, SEQ, (long)SEQ * SEQ, nullptr, 0.03125f, 1024);

    // K3: masked softmax rows (mask==0 -> 1e-10, f32 math, bf16 storage)
    softmax2048<<<dim3(NB * SEQ), 256, 0, stream>>>(sc, mask);

    // K4: attn[b] = P[b] @ V[b]   (M=2048, N=1024, K=2048), bf16 out
    //     256x128 tile -> 8x8x4 = 256 blocks
    gemm256n128<0><<<dim3(8, 8, NB), 512, 0, stream>>>(
        sc, SEQ, (long)SEQ * SEQ, vt, SEQ, (long)1024 * SEQ,
        attn, 1024, (long)SEQ * 1024, nullptr, 1.f, 2048);

    // K5: out = attn @ Wout + bout   (M=8192, N=1024, K=1024), f32 out
    //     256x128 tile -> 8x32 = 256 blocks
    gemm256n128<2><<<dim3(8, 32, 1), 512, 0, stream>>>(
        attn, 1024, 0, wot, 1024, 0, out, 1024, 0, bout, 1.f, 1024);
}